// Round 1
// baseline (875.998 us; speedup 1.0000x reference)
//
#include <hip/hip_runtime.h>
#include <hip/hip_bf16.h>

// ---------------------------------------------------------------------------
// 2-layer GCN (PyG GCNConv semantics) on N=100000 nodes, E=3.2M edges.
// Strategy: build CSR grouped by dst once per call, then pull-based
// aggregation (no fp atomics in the hot loops). Normalization folded into
// GEMM epilogue: h_scaled[j] = dis[j] * (x[j] @ W).
// out[i] = dis[i] * (h_scaled[i] + sum_{e: j->i} h_scaled[j]) + b  (+relu L1)
// ---------------------------------------------------------------------------

#define NF 128
#define HID 32
#define EMB 64

// --- edge dtype detection: flag=0 -> int64 layout, flag=1 -> int32 layout ---
__global__ void k_detect(const unsigned* __restrict__ raw, int* __restrict__ flag) {
    int t = blockIdx.x * blockDim.x + threadIdx.x;   // 4096 threads
    unsigned w = raw[2 * t + 1];                     // high word if int64
    if (w != 0u) atomicOr(flag, 1);
}

// --- convert edges to int32 src/dst and histogram dst counts ---
__global__ __launch_bounds__(256) void k_convert(const void* __restrict__ ei,
                                                 const int* __restrict__ flag,
                                                 int* __restrict__ src,
                                                 int* __restrict__ dst,
                                                 int* __restrict__ cnt, int E) {
    int i = blockIdx.x * 256 + threadIdx.x;
    if (i >= E) return;
    int s, d;
    if (*flag == 0) {
        const long long* p = (const long long*)ei;
        s = (int)p[i];
        d = (int)p[(size_t)E + i];
    } else {
        const int* p = (const int*)ei;
        s = p[i];
        d = p[E + i];
    }
    src[i] = s;
    dst[i] = d;
    atomicAdd(&cnt[d], 1);
}

// --- 3-phase exclusive scan over cnt[N] -> roff[N+1] (and cursor copy) ---
__global__ __launch_bounds__(256) void k_scan_p1(const int* __restrict__ cnt,
                                                 int* __restrict__ bsum, int N) {
    __shared__ int red[256];
    const int t = threadIdx.x;
    int base = blockIdx.x * 1024;
    int s = 0;
    for (int i = t; i < 1024; i += 256) {
        int idx = base + i;
        s += (idx < N) ? cnt[idx] : 0;
    }
    red[t] = s;
    __syncthreads();
    for (int o = 128; o > 0; o >>= 1) {
        if (t < o) red[t] += red[t + o];
        __syncthreads();
    }
    if (t == 0) bsum[blockIdx.x] = red[0];
}

__global__ void k_scan_p2(int* __restrict__ bsum, int nb) {
    __shared__ int sh[128];
    const int t = threadIdx.x;  // blockDim = 128, requires nb <= 128
    int v = (t < nb) ? bsum[t] : 0;
    sh[t] = v;
    __syncthreads();
    for (int off = 1; off < 128; off <<= 1) {
        int add = (t >= off) ? sh[t - off] : 0;
        __syncthreads();
        sh[t] += add;
        __syncthreads();
    }
    if (t < nb) bsum[t] = sh[t] - v;  // exclusive
}

__global__ __launch_bounds__(256) void k_scan_p3(const int* __restrict__ cnt,
                                                 const int* __restrict__ bsumx,
                                                 int* __restrict__ roff,
                                                 int* __restrict__ cursor,
                                                 int N, int E) {
    __shared__ int tsum[256];
    const int t = threadIdx.x;
    const int base = blockIdx.x * 1024 + t * 4;
    int v0 = (base + 0 < N) ? cnt[base + 0] : 0;
    int v1 = (base + 1 < N) ? cnt[base + 1] : 0;
    int v2 = (base + 2 < N) ? cnt[base + 2] : 0;
    int v3 = (base + 3 < N) ? cnt[base + 3] : 0;
    int s = v0 + v1 + v2 + v3;
    tsum[t] = s;
    __syncthreads();
    for (int off = 1; off < 256; off <<= 1) {
        int add = (t >= off) ? tsum[t - off] : 0;
        __syncthreads();
        tsum[t] += add;
        __syncthreads();
    }
    int excl = tsum[t] - s + bsumx[blockIdx.x];
    if (base + 0 < N) { roff[base + 0] = excl; cursor[base + 0] = excl; } excl += v0;
    if (base + 1 < N) { roff[base + 1] = excl; cursor[base + 1] = excl; } excl += v1;
    if (base + 2 < N) { roff[base + 2] = excl; cursor[base + 2] = excl; } excl += v2;
    if (base + 3 < N) { roff[base + 3] = excl; cursor[base + 3] = excl; }
    if (blockIdx.x == 0 && t == 0) roff[N] = E;
}

// --- deg_inv_sqrt (self-loop included: deg = cnt + 1 >= 1) ---
__global__ __launch_bounds__(256) void k_dis(const int* __restrict__ cnt,
                                             float* __restrict__ dis, int N) {
    int i = blockIdx.x * 256 + threadIdx.x;
    if (i < N) dis[i] = rsqrtf((float)(cnt[i] + 1));
}

// --- bin edges into CSR ---
__global__ __launch_bounds__(256) void k_fill(const int* __restrict__ src,
                                              const int* __restrict__ dst,
                                              int* __restrict__ cursor,
                                              int* __restrict__ csr, int E) {
    int i = blockIdx.x * 256 + threadIdx.x;
    if (i >= E) return;
    int d = dst[i];
    int pos = atomicAdd(&cursor[d], 1);
    csr[pos] = src[i];
}

// --- GEMM1: h1s[r] = dis[r] * (x[r] @ W1), x: N x 128, W1: 128 x 32 ---
__global__ __launch_bounds__(256) void k_gemm1(const float* __restrict__ x,
                                               const float* __restrict__ W,
                                               const float* __restrict__ dis,
                                               float* __restrict__ h1s, int N) {
    __shared__ float sW[NF * HID];     // 16 KB
    __shared__ float sx[32][132];      // padded: bank (4r+k)%32, conflict-free
    const int t = threadIdx.x;
    for (int i = t; i < NF * HID; i += 256) sW[i] = W[i];
    const int row0 = blockIdx.x * 32;
    {
        const float4* xv = (const float4*)(x + (size_t)row0 * NF);
        for (int i = t; i < 32 * 32; i += 256) {  // 32 rows x 32 float4
            int r = i >> 5, c = i & 31;
            float4 v = make_float4(0.f, 0.f, 0.f, 0.f);
            if (row0 + r < N) v = xv[(size_t)r * 32 + c];
            *(float4*)&sx[r][c * 4] = v;
        }
    }
    __syncthreads();
    const int col4 = (t & 7) * 4;
    const int row = t >> 3;
    float a0 = 0.f, a1 = 0.f, a2 = 0.f, a3 = 0.f;
#pragma unroll 8
    for (int k = 0; k < NF; ++k) {
        float xs = sx[row][k];
        float4 w = *(const float4*)&sW[k * HID + col4];
        a0 += xs * w.x; a1 += xs * w.y; a2 += xs * w.z; a3 += xs * w.w;
    }
    int r = row0 + row;
    if (r < N) {
        float d = dis[r];
        float4 o = make_float4(a0 * d, a1 * d, a2 * d, a3 * d);
        *(float4*)&h1s[(size_t)r * HID + col4] = o;
    }
}

// --- agg1: out1 = relu(dis[i]*(h1s[i] + sum_in h1s[src]) + b1), 32 ch ---
__global__ __launch_bounds__(256) void k_agg1(const float* __restrict__ h1s,
                                              const int* __restrict__ roff,
                                              const int* __restrict__ csr,
                                              const float* __restrict__ dis,
                                              const float* __restrict__ b1,
                                              float* __restrict__ out1, int N) {
    int t = blockIdx.x * 256 + threadIdx.x;
    int node = t >> 5;
    if (node >= N) return;
    int c = t & 31;
    float acc = h1s[(size_t)node * HID + c];  // self-loop term
    int e0 = roff[node], e1 = roff[node + 1];
    for (int e = e0; e < e1; ++e) {
        int s = csr[e];
        acc += h1s[(size_t)s * HID + c];
    }
    float v = dis[node] * acc + b1[c];
    out1[(size_t)node * HID + c] = fmaxf(v, 0.0f);
}

// --- GEMM2: h2s[r] = dis[r] * (out1[r] @ W2), out1: N x 32, W2: 32 x 64 ---
__global__ __launch_bounds__(256) void k_gemm2(const float* __restrict__ a,
                                               const float* __restrict__ W,
                                               const float* __restrict__ dis,
                                               float* __restrict__ h2s, int N) {
    __shared__ float sW[HID * EMB];    // 8 KB
    __shared__ float sx[32][36];       // padded
    const int t = threadIdx.x;
    for (int i = t; i < HID * EMB; i += 256) sW[i] = W[i];
    const int row0 = blockIdx.x * 32;
    {
        const float4* av = (const float4*)(a + (size_t)row0 * HID);
        // 32 rows x 8 float4 = 256 loads, 1 per thread
        int r = t >> 3, c = t & 7;
        float4 v = make_float4(0.f, 0.f, 0.f, 0.f);
        if (row0 + r < N) v = av[(size_t)r * 8 + c];
        *(float4*)&sx[r][c * 4] = v;
    }
    __syncthreads();
    const int col4 = (t & 15) * 4;
    const int r0 = t >> 4;  // 0..15; also handles r0+16
    float a00 = 0.f, a01 = 0.f, a02 = 0.f, a03 = 0.f;
    float a10 = 0.f, a11 = 0.f, a12 = 0.f, a13 = 0.f;
#pragma unroll
    for (int k = 0; k < HID; ++k) {
        float4 w = *(const float4*)&sW[k * EMB + col4];
        float xa = sx[r0][k];
        float xb = sx[r0 + 16][k];
        a00 += xa * w.x; a01 += xa * w.y; a02 += xa * w.z; a03 += xa * w.w;
        a10 += xb * w.x; a11 += xb * w.y; a12 += xb * w.z; a13 += xb * w.w;
    }
    int ra = row0 + r0, rb = row0 + r0 + 16;
    if (ra < N) {
        float d = dis[ra];
        *(float4*)&h2s[(size_t)ra * EMB + col4] =
            make_float4(a00 * d, a01 * d, a02 * d, a03 * d);
    }
    if (rb < N) {
        float d = dis[rb];
        *(float4*)&h2s[(size_t)rb * EMB + col4] =
            make_float4(a10 * d, a11 * d, a12 * d, a13 * d);
    }
}

// --- agg2: out = dis[i]*(h2s[i] + sum_in h2s[src]) + b2, 64 ch ---
__global__ __launch_bounds__(256) void k_agg2(const float* __restrict__ h2s,
                                              const int* __restrict__ roff,
                                              const int* __restrict__ csr,
                                              const float* __restrict__ dis,
                                              const float* __restrict__ b2,
                                              float* __restrict__ out, int N) {
    int t = blockIdx.x * 256 + threadIdx.x;
    int node = t >> 6;
    if (node >= N) return;
    int c = t & 63;
    float acc = h2s[(size_t)node * EMB + c];  // self-loop term
    int e0 = roff[node], e1 = roff[node + 1];
    for (int e = e0; e < e1; ++e) {
        int s = csr[e];
        acc += h2s[(size_t)s * EMB + c];
    }
    out[(size_t)node * EMB + c] = dis[node] * acc + b2[c];
}

extern "C" void kernel_launch(void* const* d_in, const int* in_sizes, int n_in,
                              void* d_out, int out_size, void* d_ws, size_t ws_size,
                              hipStream_t stream) {
    const float* x  = (const float*)d_in[0];
    const void*  ei = d_in[1];
    const float* W1 = (const float*)d_in[2];
    const float* b1 = (const float*)d_in[3];
    const float* W2 = (const float*)d_in[4];
    const float* b2 = (const float*)d_in[5];
    float* out = (float*)d_out;

    const int N = in_sizes[0] / NF;   // 100000
    const int E = in_sizes[1] / 2;    // 3200000

    // workspace carve-up (256B aligned)
    char* ws = (char*)d_ws;
    size_t off = 0;
    auto take = [&](size_t bytes) -> void* {
        void* p = ws + off;
        off += (bytes + 255) & ~(size_t)255;
        return p;
    };
    int*   flag   = (int*)take(4);
    int*   cnt    = (int*)take((size_t)N * 4);
    int*   roff   = (int*)take((size_t)(N + 1) * 4);
    int*   cursor = (int*)take((size_t)N * 4);
    int*   bsum   = (int*)take(1024);
    float* dis    = (float*)take((size_t)N * 4);
    int*   src32  = (int*)take((size_t)E * 4);
    int*   dst32  = (int*)take((size_t)E * 4);
    int*   csr    = (int*)take((size_t)E * 4);
    float* h1s    = (float*)take((size_t)N * HID * 4);
    float* out1   = (float*)take((size_t)N * HID * 4);
    float* h2s    = (float*)take((size_t)N * EMB * 4);

    hipMemsetAsync(flag, 0, 4, stream);
    hipMemsetAsync(cnt, 0, (size_t)N * 4, stream);

    const int EB = (E + 255) / 256;
    const int NB1024 = (N + 1023) / 1024;  // 98 (<=128 required by scan_p2)

    k_detect<<<16, 256, 0, stream>>>((const unsigned*)ei, flag);
    k_convert<<<EB, 256, 0, stream>>>(ei, flag, src32, dst32, cnt, E);
    k_scan_p1<<<NB1024, 256, 0, stream>>>(cnt, bsum, N);
    k_scan_p2<<<1, 128, 0, stream>>>(bsum, NB1024);
    k_scan_p3<<<NB1024, 256, 0, stream>>>(cnt, bsum, roff, cursor, N, E);
    k_dis<<<(N + 255) / 256, 256, 0, stream>>>(cnt, dis, N);
    k_fill<<<EB, 256, 0, stream>>>(src32, dst32, cursor, csr, E);

    k_gemm1<<<(N + 31) / 32, 256, 0, stream>>>(x, W1, dis, h1s, N);
    k_agg1<<<((size_t)N * HID + 255) / 256, 256, 0, stream>>>(h1s, roff, csr, dis, b1, out1, N);
    k_gemm2<<<(N + 31) / 32, 256, 0, stream>>>(out1, W2, dis, h2s, N);
    k_agg2<<<((size_t)N * EMB + 255) / 256, 256, 0, stream>>>(h2s, roff, csr, dis, b2, out, N);
}

// Round 3
// 524.478 us; speedup vs baseline: 1.6702x; 1.6702x over previous
//
#include <hip/hip_runtime.h>
#include <hip/hip_bf16.h>

// ---------------------------------------------------------------------------
// 2-layer GCN (PyG GCNConv) N=100000, E=3.2M.
// CSR-by-dst build with XCD-localized scatter (XCC_ID work-steal + fallback
// sweep for correctness independence), then pull-based aggregation with
// x4-unrolled gather loops. Layer-2 features stored as packed bf16.
// ---------------------------------------------------------------------------

#define NF 128
#define HID 32
#define EMB 64
#define FCHUNK 8192

typedef float vf4 __attribute__((ext_vector_type(4)));

static __device__ __forceinline__ unsigned bf16rne(float f) {
    unsigned u = __float_as_uint(f);
    return (u + 0x7fffu + ((u >> 16) & 1u)) >> 16;
}

// --- edge dtype detection: flag=0 -> int64, flag=1 -> int32 ---
__global__ void k_detect(const unsigned* __restrict__ raw, int* __restrict__ flag) {
    int t = blockIdx.x * blockDim.x + threadIdx.x;   // 4096 threads
    unsigned w = raw[2 * t + 1];                     // high word if int64
    if (w != 0u) atomicOr(flag, 1);
}

// --- convert edges to int32 src/dst and histogram dst counts ---
__global__ __launch_bounds__(256) void k_convert(const void* __restrict__ ei,
                                                 const int* __restrict__ flag,
                                                 int* __restrict__ src,
                                                 int* __restrict__ dst,
                                                 int* __restrict__ cnt, int E) {
    int i = blockIdx.x * 256 + threadIdx.x;
    if (i >= E) return;
    int s, d;
    if (*flag == 0) {
        const long long* p = (const long long*)ei;
        s = (int)__builtin_nontemporal_load(&p[i]);
        d = (int)__builtin_nontemporal_load(&p[(size_t)E + i]);
    } else {
        const int* p = (const int*)ei;
        s = __builtin_nontemporal_load(&p[i]);
        d = __builtin_nontemporal_load(&p[E + i]);
    }
    src[i] = s;
    dst[i] = d;
    atomicAdd(&cnt[d], 1);
}

// --- 3-phase exclusive scan cnt[N] -> roff[N+1], cursor copy, dis fused ---
__global__ __launch_bounds__(256) void k_scan_p1(const int* __restrict__ cnt,
                                                 int* __restrict__ bsum, int N) {
    __shared__ int red[256];
    const int t = threadIdx.x;
    int base = blockIdx.x * 1024;
    int s = 0;
    for (int i = t; i < 1024; i += 256) {
        int idx = base + i;
        s += (idx < N) ? cnt[idx] : 0;
    }
    red[t] = s;
    __syncthreads();
    for (int o = 128; o > 0; o >>= 1) {
        if (t < o) red[t] += red[t + o];
        __syncthreads();
    }
    if (t == 0) bsum[blockIdx.x] = red[0];
}

__global__ void k_scan_p2(int* __restrict__ bsum, int nb) {
    __shared__ int sh[128];
    const int t = threadIdx.x;  // blockDim=128, nb<=128
    int v = (t < nb) ? bsum[t] : 0;
    sh[t] = v;
    __syncthreads();
    for (int off = 1; off < 128; off <<= 1) {
        int add = (t >= off) ? sh[t - off] : 0;
        __syncthreads();
        sh[t] += add;
        __syncthreads();
    }
    if (t < nb) bsum[t] = sh[t] - v;  // exclusive
}

__global__ __launch_bounds__(256) void k_scan_p3(const int* __restrict__ cnt,
                                                 const int* __restrict__ bsumx,
                                                 int* __restrict__ roff,
                                                 int* __restrict__ cursor,
                                                 float* __restrict__ dis,
                                                 int N, int E) {
    __shared__ int tsum[256];
    const int t = threadIdx.x;
    const int base = blockIdx.x * 1024 + t * 4;
    int v0 = (base + 0 < N) ? cnt[base + 0] : 0;
    int v1 = (base + 1 < N) ? cnt[base + 1] : 0;
    int v2 = (base + 2 < N) ? cnt[base + 2] : 0;
    int v3 = (base + 3 < N) ? cnt[base + 3] : 0;
    int s = v0 + v1 + v2 + v3;
    tsum[t] = s;
    __syncthreads();
    for (int off = 1; off < 256; off <<= 1) {
        int add = (t >= off) ? tsum[t - off] : 0;
        __syncthreads();
        tsum[t] += add;
        __syncthreads();
    }
    int excl = tsum[t] - s + bsumx[blockIdx.x];
    if (base + 0 < N) { roff[base + 0] = excl; cursor[base + 0] = excl; dis[base + 0] = rsqrtf((float)(v0 + 1)); } excl += v0;
    if (base + 1 < N) { roff[base + 1] = excl; cursor[base + 1] = excl; dis[base + 1] = rsqrtf((float)(v1 + 1)); } excl += v1;
    if (base + 2 < N) { roff[base + 2] = excl; cursor[base + 2] = excl; dis[base + 2] = rsqrtf((float)(v2 + 1)); } excl += v2;
    if (base + 3 < N) { roff[base + 3] = excl; cursor[base + 3] = excl; dis[base + 3] = rsqrtf((float)(v3 + 1)); }
    if (blockIdx.x == 0 && t == 0) roff[N] = E;
}

// --- XCD-localized CSR fill: block handles only dst slabs owned by its XCD.
// Work-steal chunks via per-XCD counters; mark done[] for the fallback sweep.
__global__ __launch_bounds__(256) void k_fill_x(const int* __restrict__ src,
                                                const int* __restrict__ dst,
                                                int* __restrict__ cursor,
                                                int* __restrict__ csr,
                                                int* __restrict__ ctr,
                                                int* __restrict__ done,
                                                int E, int nchunk) {
    __shared__ int sc;
    int k = __builtin_amdgcn_s_getreg((31 << 11) | (0 << 6) | 20) & 7;  // HW_REG_XCC_ID
    for (;;) {
        __syncthreads();
        if (threadIdx.x == 0) sc = atomicAdd(&ctr[k], 1);
        __syncthreads();
        int c = sc;
        if (c >= nchunk) break;
        int base = c * FCHUNK;
        int end = min(E, base + FCHUNK);
        for (int i = base + threadIdx.x; i < end; i += 256) {
            int d = __builtin_nontemporal_load(&dst[i]);
            if (((d >> 12) & 7) == k) {
                int pos = atomicAdd(&cursor[d], 1);
                csr[pos] = __builtin_nontemporal_load(&src[i]);
            }
        }
        __syncthreads();
        if (threadIdx.x == 0) done[c * 8 + k] = 1;
    }
}

// --- fallback sweep: process any (chunk, range) pair k_fill_x missed ---
__global__ __launch_bounds__(256) void k_fill_fb(const int* __restrict__ src,
                                                 const int* __restrict__ dst,
                                                 int* __restrict__ cursor,
                                                 int* __restrict__ csr,
                                                 const int* __restrict__ done,
                                                 int E) {
    int b = blockIdx.x;
    if (done[b]) return;
    int c = b >> 3, k = b & 7;
    int base = c * FCHUNK;
    int end = min(E, base + FCHUNK);
    for (int i = base + threadIdx.x; i < end; i += 256) {
        int d = dst[i];
        if (((d >> 12) & 7) == k) {
            int pos = atomicAdd(&cursor[d], 1);
            csr[pos] = src[i];
        }
    }
}

// --- GEMM1: h1s[r] = dis[r] * (x[r] @ W1), x: N x 128, W1: 128 x 32 ---
__global__ __launch_bounds__(256) void k_gemm1(const float* __restrict__ x,
                                               const float* __restrict__ W,
                                               const float* __restrict__ dis,
                                               float* __restrict__ h1s, int N) {
    __shared__ float sW[NF * HID];     // 16 KB
    __shared__ float sx[32][132];
    const int t = threadIdx.x;
    for (int i = t; i < NF * HID; i += 256) sW[i] = W[i];
    const int row0 = blockIdx.x * 32;
    {
        const float4* xv = (const float4*)(x + (size_t)row0 * NF);
        for (int i = t; i < 32 * 32; i += 256) {
            int r = i >> 5, c = i & 31;
            float4 v = make_float4(0.f, 0.f, 0.f, 0.f);
            if (row0 + r < N) v = xv[(size_t)r * 32 + c];
            *(float4*)&sx[r][c * 4] = v;
        }
    }
    __syncthreads();
    const int col4 = (t & 7) * 4;
    const int row = t >> 3;
    float a0 = 0.f, a1 = 0.f, a2 = 0.f, a3 = 0.f;
#pragma unroll 8
    for (int k = 0; k < NF; ++k) {
        float xs = sx[row][k];
        float4 w = *(const float4*)&sW[k * HID + col4];
        a0 += xs * w.x; a1 += xs * w.y; a2 += xs * w.z; a3 += xs * w.w;
    }
    int r = row0 + row;
    if (r < N) {
        float d = dis[r];
        *(float4*)&h1s[(size_t)r * HID + col4] = make_float4(a0 * d, a1 * d, a2 * d, a3 * d);
    }
}

// --- agg1: out1 = relu(dis[i]*(h1s[i] + sum_in h1s[src]) + b1), 32 ch ---
// 8 lanes/node, float4/lane, degree loop unrolled x4
__global__ __launch_bounds__(256) void k_agg1(const float* __restrict__ h1s,
                                              const int* __restrict__ roff,
                                              const int* __restrict__ csr,
                                              const float* __restrict__ dis,
                                              const float* __restrict__ b1,
                                              float* __restrict__ out1, int N) {
    int t = blockIdx.x * 256 + threadIdx.x;
    int node = t >> 3;
    if (node >= N) return;
    int j = t & 7;
    const float4* h4 = (const float4*)h1s;   // row stride 8
    float4 v = h4[(size_t)node * 8 + j];     // self-loop
    float a0 = v.x, a1 = v.y, a2 = v.z, a3 = v.w;
    int e0 = roff[node], e1 = roff[node + 1];
    int e = e0;
    for (; e + 4 <= e1; e += 4) {
        int s0 = __builtin_nontemporal_load(&csr[e + 0]);
        int s1 = __builtin_nontemporal_load(&csr[e + 1]);
        int s2 = __builtin_nontemporal_load(&csr[e + 2]);
        int s3 = __builtin_nontemporal_load(&csr[e + 3]);
        float4 v0 = h4[(size_t)s0 * 8 + j];
        float4 v1 = h4[(size_t)s1 * 8 + j];
        float4 v2 = h4[(size_t)s2 * 8 + j];
        float4 v3 = h4[(size_t)s3 * 8 + j];
        a0 += v0.x + v1.x + v2.x + v3.x;
        a1 += v0.y + v1.y + v2.y + v3.y;
        a2 += v0.z + v1.z + v2.z + v3.z;
        a3 += v0.w + v1.w + v2.w + v3.w;
    }
    for (; e < e1; ++e) {
        int s = __builtin_nontemporal_load(&csr[e]);
        float4 w = h4[(size_t)s * 8 + j];
        a0 += w.x; a1 += w.y; a2 += w.z; a3 += w.w;
    }
    float d = dis[node];
    float4 bb = *(const float4*)&b1[j * 4];
    float4 o = make_float4(fmaxf(a0 * d + bb.x, 0.f), fmaxf(a1 * d + bb.y, 0.f),
                           fmaxf(a2 * d + bb.z, 0.f), fmaxf(a3 * d + bb.w, 0.f));
    *(float4*)&out1[(size_t)node * HID + j * 4] = o;
}

// --- GEMM2: h2b[r] = pack_bf16(dis[r] * (out1[r] @ W2)), W2: 32 x 64 ---
__global__ __launch_bounds__(256) void k_gemm2(const float* __restrict__ a,
                                               const float* __restrict__ W,
                                               const float* __restrict__ dis,
                                               unsigned* __restrict__ h2b, int N) {
    __shared__ float sW[HID * EMB];
    __shared__ float sx[32][36];
    const int t = threadIdx.x;
    for (int i = t; i < HID * EMB; i += 256) sW[i] = W[i];
    const int row0 = blockIdx.x * 32;
    {
        const float4* av = (const float4*)(a + (size_t)row0 * HID);
        int r = t >> 3, c = t & 7;
        float4 v = make_float4(0.f, 0.f, 0.f, 0.f);
        if (row0 + r < N) v = av[(size_t)r * 8 + c];
        *(float4*)&sx[r][c * 4] = v;
    }
    __syncthreads();
    const int col4 = (t & 15) * 4;
    const int r0 = t >> 4;  // 0..15, also r0+16
    float a00 = 0.f, a01 = 0.f, a02 = 0.f, a03 = 0.f;
    float a10 = 0.f, a11 = 0.f, a12 = 0.f, a13 = 0.f;
#pragma unroll
    for (int k = 0; k < HID; ++k) {
        float4 w = *(const float4*)&sW[k * EMB + col4];
        float xa = sx[r0][k];
        float xb = sx[r0 + 16][k];
        a00 += xa * w.x; a01 += xa * w.y; a02 += xa * w.z; a03 += xa * w.w;
        a10 += xb * w.x; a11 += xb * w.y; a12 += xb * w.z; a13 += xb * w.w;
    }
    int ra = row0 + r0, rb = row0 + r0 + 16;
    int ju = (t & 15) * 2;  // uint index within row (32 uints/row)
    if (ra < N) {
        float d = dis[ra];
        unsigned u0 = bf16rne(a00 * d) | (bf16rne(a01 * d) << 16);
        unsigned u1 = bf16rne(a02 * d) | (bf16rne(a03 * d) << 16);
        *(uint2*)&h2b[(size_t)ra * 32 + ju] = make_uint2(u0, u1);
    }
    if (rb < N) {
        float d = dis[rb];
        unsigned u0 = bf16rne(a10 * d) | (bf16rne(a11 * d) << 16);
        unsigned u1 = bf16rne(a12 * d) | (bf16rne(a13 * d) << 16);
        *(uint2*)&h2b[(size_t)rb * 32 + ju] = make_uint2(u0, u1);
    }
}

// --- agg2: out = dis[i]*(h2b[i] + sum_in h2b[src]) + b2, 64 ch bf16-packed ---
// 16 lanes/node, uint2 (4 ch)/lane, degree loop unrolled x4
__global__ __launch_bounds__(256) void k_agg2(const unsigned* __restrict__ h2b,
                                              const int* __restrict__ roff,
                                              const int* __restrict__ csr,
                                              const float* __restrict__ dis,
                                              const float* __restrict__ b2,
                                              float* __restrict__ out, int N) {
    int t = blockIdx.x * 256 + threadIdx.x;
    int node = t >> 4;
    if (node >= N) return;
    int j = t & 15;
    const uint2* hb = (const uint2*)h2b;     // row stride 16 uint2
    uint2 u = hb[(size_t)node * 16 + j];     // self-loop
    float a0 = __uint_as_float(u.x << 16);
    float a1 = __uint_as_float(u.x & 0xffff0000u);
    float a2 = __uint_as_float(u.y << 16);
    float a3 = __uint_as_float(u.y & 0xffff0000u);
    int e0 = roff[node], e1 = roff[node + 1];
    int e = e0;
    for (; e + 4 <= e1; e += 4) {
        int s0 = __builtin_nontemporal_load(&csr[e + 0]);
        int s1 = __builtin_nontemporal_load(&csr[e + 1]);
        int s2 = __builtin_nontemporal_load(&csr[e + 2]);
        int s3 = __builtin_nontemporal_load(&csr[e + 3]);
        uint2 v0 = hb[(size_t)s0 * 16 + j];
        uint2 v1 = hb[(size_t)s1 * 16 + j];
        uint2 v2 = hb[(size_t)s2 * 16 + j];
        uint2 v3 = hb[(size_t)s3 * 16 + j];
        a0 += __uint_as_float(v0.x << 16) + __uint_as_float(v1.x << 16) +
              __uint_as_float(v2.x << 16) + __uint_as_float(v3.x << 16);
        a1 += __uint_as_float(v0.x & 0xffff0000u) + __uint_as_float(v1.x & 0xffff0000u) +
              __uint_as_float(v2.x & 0xffff0000u) + __uint_as_float(v3.x & 0xffff0000u);
        a2 += __uint_as_float(v0.y << 16) + __uint_as_float(v1.y << 16) +
              __uint_as_float(v2.y << 16) + __uint_as_float(v3.y << 16);
        a3 += __uint_as_float(v0.y & 0xffff0000u) + __uint_as_float(v1.y & 0xffff0000u) +
              __uint_as_float(v2.y & 0xffff0000u) + __uint_as_float(v3.y & 0xffff0000u);
    }
    for (; e < e1; ++e) {
        int s = __builtin_nontemporal_load(&csr[e]);
        uint2 v = hb[(size_t)s * 16 + j];
        a0 += __uint_as_float(v.x << 16);
        a1 += __uint_as_float(v.x & 0xffff0000u);
        a2 += __uint_as_float(v.y << 16);
        a3 += __uint_as_float(v.y & 0xffff0000u);
    }
    float d = dis[node];
    float4 bb = *(const float4*)&b2[j * 4];
    vf4 o;
    o.x = a0 * d + bb.x; o.y = a1 * d + bb.y;
    o.z = a2 * d + bb.z; o.w = a3 * d + bb.w;
    __builtin_nontemporal_store(o, (vf4*)&out[(size_t)node * EMB + j * 4]);
}

extern "C" void kernel_launch(void* const* d_in, const int* in_sizes, int n_in,
                              void* d_out, int out_size, void* d_ws, size_t ws_size,
                              hipStream_t stream) {
    const float* x  = (const float*)d_in[0];
    const void*  ei = d_in[1];
    const float* W1 = (const float*)d_in[2];
    const float* b1 = (const float*)d_in[3];
    const float* W2 = (const float*)d_in[4];
    const float* b2 = (const float*)d_in[5];
    float* out = (float*)d_out;

    const int N = in_sizes[0] / NF;   // 100000
    const int E = in_sizes[1] / 2;    // 3200000
    const int nchunk = (E + FCHUNK - 1) / FCHUNK;

    char* ws = (char*)d_ws;
    size_t off = 0;
    auto take = [&](size_t bytes) -> void* {
        void* p = ws + off;
        off += (bytes + 255) & ~(size_t)255;
        return p;
    };
    // zeroed region first (single memset)
    int*   cnt    = (int*)take((size_t)N * 4);
    int*   flag   = (int*)take(4);
    int*   ctr    = (int*)take(8 * 4);
    int*   done   = (int*)take((size_t)nchunk * 8 * 4);
    size_t zbytes = off;
    // rest
    int*      roff   = (int*)take((size_t)(N + 1) * 4);
    int*      cursor = (int*)take((size_t)N * 4);
    int*      bsum   = (int*)take(1024);
    float*    dis    = (float*)take((size_t)N * 4);
    int*      src32  = (int*)take((size_t)E * 4);
    int*      dst32  = (int*)take((size_t)E * 4);
    int*      csr    = (int*)take((size_t)E * 4);
    float*    h1s    = (float*)take((size_t)N * HID * 4);
    float*    out1   = (float*)take((size_t)N * HID * 4);
    unsigned* h2b    = (unsigned*)take((size_t)N * EMB * 2);

    (void)hipMemsetAsync(cnt, 0, zbytes, stream);

    const int EB = (E + 255) / 256;
    const int NB1024 = (N + 1023) / 1024;  // 98 (<=128 for scan_p2)

    k_detect<<<16, 256, 0, stream>>>((const unsigned*)ei, flag);
    k_convert<<<EB, 256, 0, stream>>>(ei, flag, src32, dst32, cnt, E);
    k_scan_p1<<<NB1024, 256, 0, stream>>>(cnt, bsum, N);
    k_scan_p2<<<1, 128, 0, stream>>>(bsum, NB1024);
    k_scan_p3<<<NB1024, 256, 0, stream>>>(cnt, bsum, roff, cursor, dis, N, E);
    k_fill_x<<<2048, 256, 0, stream>>>(src32, dst32, cursor, csr, ctr, done, E, nchunk);
    k_fill_fb<<<nchunk * 8, 256, 0, stream>>>(src32, dst32, cursor, csr, done, E);

    k_gemm1<<<(N + 31) / 32, 256, 0, stream>>>(x, W1, dis, h1s, N);
    k_agg1<<<((size_t)N * 8 + 255) / 256, 256, 0, stream>>>(h1s, roff, csr, dis, b1, out1, N);
    k_gemm2<<<(N + 31) / 32, 256, 0, stream>>>(out1, W2, dis, h2b, N);
    k_agg2<<<((size_t)N * 16 + 255) / 256, 256, 0, stream>>>(h2b, roff, csr, dis, b2, out, N);
}

// Round 4
// 492.148 us; speedup vs baseline: 1.7799x; 1.0657x over previous
//
#include <hip/hip_runtime.h>
#include <hip/hip_bf16.h>

// ---------------------------------------------------------------------------
// 2-layer GCN (PyG GCNConv) N=100000, E=3.2M.
// Fill: LDS-staged 391-way multisplit by dst>>8 into per-bucket pair regions
// (coalesced), then per-bucket L2-resident scatter into CSR. Pull-based
// aggregation, layer-2 features packed bf16.
// ---------------------------------------------------------------------------

#define NF 128
#define HID 32
#define EMB 64

#define BSHIFT 8            // 256 nodes per bucket
#define CAP 10240           // max edges stored per bucket (mean 8192 + 22 sigma)
#define NBUKMAX 400         // >= ceil(100000/256)=391
#define TILE 4096
#define OVFCAP (1 << 20)

typedef float vf4 __attribute__((ext_vector_type(4)));

static __device__ __forceinline__ unsigned bf16rne(float f) {
    unsigned u = __float_as_uint(f);
    return (u + 0x7fffu + ((u >> 16) & 1u)) >> 16;
}

// --- edge dtype detection: flag=0 -> int64, flag=1 -> int32 ---
__global__ void k_detect(const unsigned* __restrict__ raw, int* __restrict__ flag) {
    int t = blockIdx.x * blockDim.x + threadIdx.x;   // 4096 threads
    unsigned w = raw[2 * t + 1];                     // high word if int64
    if (w != 0u) atomicOr(flag, 1);
}

// --- multisplit edges into 256-node dst-buckets + per-node histogram ---
__global__ __launch_bounds__(256) void k_part(const void* __restrict__ ei,
                                              const int* __restrict__ flag,
                                              unsigned long long* __restrict__ pairs,
                                              int* __restrict__ bcur,
                                              int* __restrict__ cnt,
                                              unsigned long long* __restrict__ ovf,
                                              int* __restrict__ ovfcnt,
                                              int E, int nbuk) {
    __shared__ unsigned long long sPair[TILE];     // 32 KB
    __shared__ unsigned sGd[TILE];                 // 16 KB
    __shared__ int hcnt[NBUKMAX], lcur[NBUKMAX], lstart[NBUKMAX], gbase[NBUKMAX];
    const int tid = threadIdx.x;
    const int tile0 = blockIdx.x * TILE;
    if (tile0 >= E) return;
    const int tcnt = min(TILE, E - tile0);
    const bool is64 = (*flag == 0);

    for (int b = tid; b < nbuk; b += 256) hcnt[b] = 0;
    __syncthreads();

    int ms[16], md[16];
#pragma unroll
    for (int k = 0; k < 16; ++k) {
        int i = tile0 + k * 256 + tid;
        ms[k] = -1;
        if (i - tile0 < tcnt) {
            int s, d;
            if (is64) {
                const long long* p = (const long long*)ei;
                s = (int)__builtin_nontemporal_load(&p[i]);
                d = (int)__builtin_nontemporal_load(&p[(size_t)E + i]);
            } else {
                const int* p = (const int*)ei;
                s = __builtin_nontemporal_load(&p[i]);
                d = __builtin_nontemporal_load(&p[E + i]);
            }
            ms[k] = s; md[k] = d;
            atomicAdd(&hcnt[d >> BSHIFT], 1);
            atomicAdd(&cnt[d], 1);
        }
    }
    __syncthreads();

    if (tid < 64) {  // wave 0: scan 391 bucket counts, reserve global space
        int vpre[7]; int run = 0;
#pragma unroll
        for (int k = 0; k < 7; ++k) {
            int idx = tid * 7 + k;
            int c = (idx < nbuk) ? hcnt[idx] : 0;
            vpre[k] = run; run += c;
        }
        int inc = run;
#pragma unroll
        for (int off = 1; off < 64; off <<= 1) {
            int tt = __shfl_up(inc, off);
            if (tid >= off) inc += tt;
        }
        int excl = inc - run;
#pragma unroll
        for (int k = 0; k < 7; ++k) {
            int idx = tid * 7 + k;
            if (idx < nbuk) {
                lstart[idx] = excl + vpre[k];
                int h = hcnt[idx];
                gbase[idx] = h ? atomicAdd(&bcur[idx], h) : 0;
                lcur[idx] = 0;
            }
        }
    }
    __syncthreads();

#pragma unroll
    for (int k = 0; k < 16; ++k) {
        if (ms[k] >= 0) {
            int b = md[k] >> BSHIFT;
            int c = atomicAdd(&lcur[b], 1);
            int slot = lstart[b] + c;
            int g = gbase[b] + c;
            sPair[slot] = ((unsigned long long)(unsigned)md[k] << 32) | (unsigned)ms[k];
            sGd[slot] = (g < CAP) ? (unsigned)(b * CAP + g) : 0xFFFFFFFFu;
        }
    }
    __syncthreads();

    for (int j = tid; j < tcnt; j += 256) {   // bucket-ordered coalesced flush
        unsigned gd = sGd[j];
        unsigned long long pr = sPair[j];
        if (gd != 0xFFFFFFFFu) {
            __builtin_nontemporal_store(pr, &pairs[gd]);
        } else {
            int o = atomicAdd(ovfcnt, 1);
            if (o < OVFCAP) ovf[o] = pr;
        }
    }
}

// --- 3-phase exclusive scan cnt[N] -> roff[N+1], cursor copy, dis fused ---
__global__ __launch_bounds__(256) void k_scan_p1(const int* __restrict__ cnt,
                                                 int* __restrict__ bsum, int N) {
    __shared__ int red[256];
    const int t = threadIdx.x;
    int base = blockIdx.x * 1024;
    int s = 0;
    for (int i = t; i < 1024; i += 256) {
        int idx = base + i;
        s += (idx < N) ? cnt[idx] : 0;
    }
    red[t] = s;
    __syncthreads();
    for (int o = 128; o > 0; o >>= 1) {
        if (t < o) red[t] += red[t + o];
        __syncthreads();
    }
    if (t == 0) bsum[blockIdx.x] = red[0];
}

__global__ void k_scan_p2(int* __restrict__ bsum, int nb) {
    __shared__ int sh[128];
    const int t = threadIdx.x;  // blockDim=128, nb<=128
    int v = (t < nb) ? bsum[t] : 0;
    sh[t] = v;
    __syncthreads();
    for (int off = 1; off < 128; off <<= 1) {
        int add = (t >= off) ? sh[t - off] : 0;
        __syncthreads();
        sh[t] += add;
        __syncthreads();
    }
    if (t < nb) bsum[t] = sh[t] - v;  // exclusive
}

__global__ __launch_bounds__(256) void k_scan_p3(const int* __restrict__ cnt,
                                                 const int* __restrict__ bsumx,
                                                 int* __restrict__ roff,
                                                 int* __restrict__ cursor,
                                                 float* __restrict__ dis,
                                                 int N, int E) {
    __shared__ int tsum[256];
    const int t = threadIdx.x;
    const int base = blockIdx.x * 1024 + t * 4;
    int v0 = (base + 0 < N) ? cnt[base + 0] : 0;
    int v1 = (base + 1 < N) ? cnt[base + 1] : 0;
    int v2 = (base + 2 < N) ? cnt[base + 2] : 0;
    int v3 = (base + 3 < N) ? cnt[base + 3] : 0;
    int s = v0 + v1 + v2 + v3;
    tsum[t] = s;
    __syncthreads();
    for (int off = 1; off < 256; off <<= 1) {
        int add = (t >= off) ? tsum[t - off] : 0;
        __syncthreads();
        tsum[t] += add;
        __syncthreads();
    }
    int excl = tsum[t] - s + bsumx[blockIdx.x];
    if (base + 0 < N) { roff[base + 0] = excl; cursor[base + 0] = excl; dis[base + 0] = rsqrtf((float)(v0 + 1)); } excl += v0;
    if (base + 1 < N) { roff[base + 1] = excl; cursor[base + 1] = excl; dis[base + 1] = rsqrtf((float)(v1 + 1)); } excl += v1;
    if (base + 2 < N) { roff[base + 2] = excl; cursor[base + 2] = excl; dis[base + 2] = rsqrtf((float)(v2 + 1)); } excl += v2;
    if (base + 3 < N) { roff[base + 3] = excl; cursor[base + 3] = excl; dis[base + 3] = rsqrtf((float)(v3 + 1)); }
    if (blockIdx.x == 0 && t == 0) roff[N] = E;
}

// --- per-bucket scatter into CSR: one block per bucket, L2-resident region ---
__global__ __launch_bounds__(256) void k_scat(const unsigned long long* __restrict__ pairs,
                                              const int* __restrict__ bcur,
                                              int* __restrict__ cursor,
                                              int* __restrict__ csr) {
    int b = blockIdx.x;
    int nb = min(bcur[b], CAP);
    const unsigned long long* pp = pairs + (size_t)b * CAP;
    for (int i = threadIdx.x; i < nb; i += 256) {
        unsigned long long pr = __builtin_nontemporal_load(&pp[i]);
        int s = (int)(unsigned)pr;
        int d = (int)(unsigned)(pr >> 32);
        int pos = atomicAdd(&cursor[d], 1);
        csr[pos] = s;
    }
}

// --- overflow sweep (empty for benchmark data) ---
__global__ __launch_bounds__(256) void k_ovf(const unsigned long long* __restrict__ ovf,
                                             const int* __restrict__ ovfcnt,
                                             int* __restrict__ cursor,
                                             int* __restrict__ csr) {
    int n = min(*ovfcnt, OVFCAP);
    for (int i = blockIdx.x * 256 + threadIdx.x; i < n; i += 256 * 8) {
        unsigned long long pr = ovf[i];
        int pos = atomicAdd(&cursor[(int)(unsigned)(pr >> 32)], 1);
        csr[pos] = (int)(unsigned)pr;
    }
}

// --- GEMM1: h1s[r] = dis[r] * (x[r] @ W1), x: N x 128, W1: 128 x 32 ---
__global__ __launch_bounds__(256) void k_gemm1(const float* __restrict__ x,
                                               const float* __restrict__ W,
                                               const float* __restrict__ dis,
                                               float* __restrict__ h1s, int N) {
    __shared__ float sW[NF * HID];     // 16 KB
    __shared__ float sx[32][132];
    const int t = threadIdx.x;
    for (int i = t; i < NF * HID; i += 256) sW[i] = W[i];
    const int row0 = blockIdx.x * 32;
    {
        const float4* xv = (const float4*)(x + (size_t)row0 * NF);
        for (int i = t; i < 32 * 32; i += 256) {
            int r = i >> 5, c = i & 31;
            float4 v = make_float4(0.f, 0.f, 0.f, 0.f);
            if (row0 + r < N) v = xv[(size_t)r * 32 + c];
            *(float4*)&sx[r][c * 4] = v;
        }
    }
    __syncthreads();
    const int col4 = (t & 7) * 4;
    const int row = t >> 3;
    float a0 = 0.f, a1 = 0.f, a2 = 0.f, a3 = 0.f;
#pragma unroll 8
    for (int k = 0; k < NF; ++k) {
        float xs = sx[row][k];
        float4 w = *(const float4*)&sW[k * HID + col4];
        a0 += xs * w.x; a1 += xs * w.y; a2 += xs * w.z; a3 += xs * w.w;
    }
    int r = row0 + row;
    if (r < N) {
        float d = dis[r];
        *(float4*)&h1s[(size_t)r * HID + col4] = make_float4(a0 * d, a1 * d, a2 * d, a3 * d);
    }
}

// --- agg1: out1 = relu(dis[i]*(h1s[i] + sum_in h1s[src]) + b1), 32 ch ---
__global__ __launch_bounds__(256) void k_agg1(const float* __restrict__ h1s,
                                              const int* __restrict__ roff,
                                              const int* __restrict__ csr,
                                              const float* __restrict__ dis,
                                              const float* __restrict__ b1,
                                              float* __restrict__ out1, int N) {
    int t = blockIdx.x * 256 + threadIdx.x;
    int node = t >> 3;
    if (node >= N) return;
    int j = t & 7;
    const float4* h4 = (const float4*)h1s;   // row stride 8
    float4 v = h4[(size_t)node * 8 + j];     // self-loop
    float a0 = v.x, a1 = v.y, a2 = v.z, a3 = v.w;
    int e0 = roff[node], e1 = roff[node + 1];
    int e = e0;
    for (; e + 4 <= e1; e += 4) {
        int s0 = __builtin_nontemporal_load(&csr[e + 0]);
        int s1 = __builtin_nontemporal_load(&csr[e + 1]);
        int s2 = __builtin_nontemporal_load(&csr[e + 2]);
        int s3 = __builtin_nontemporal_load(&csr[e + 3]);
        float4 v0 = h4[(size_t)s0 * 8 + j];
        float4 v1 = h4[(size_t)s1 * 8 + j];
        float4 v2 = h4[(size_t)s2 * 8 + j];
        float4 v3 = h4[(size_t)s3 * 8 + j];
        a0 += v0.x + v1.x + v2.x + v3.x;
        a1 += v0.y + v1.y + v2.y + v3.y;
        a2 += v0.z + v1.z + v2.z + v3.z;
        a3 += v0.w + v1.w + v2.w + v3.w;
    }
    for (; e < e1; ++e) {
        int s = __builtin_nontemporal_load(&csr[e]);
        float4 w = h4[(size_t)s * 8 + j];
        a0 += w.x; a1 += w.y; a2 += w.z; a3 += w.w;
    }
    float d = dis[node];
    float4 bb = *(const float4*)&b1[j * 4];
    float4 o = make_float4(fmaxf(a0 * d + bb.x, 0.f), fmaxf(a1 * d + bb.y, 0.f),
                           fmaxf(a2 * d + bb.z, 0.f), fmaxf(a3 * d + bb.w, 0.f));
    *(float4*)&out1[(size_t)node * HID + j * 4] = o;
}

// --- GEMM2: h2b[r] = pack_bf16(dis[r] * (out1[r] @ W2)), W2: 32 x 64 ---
__global__ __launch_bounds__(256) void k_gemm2(const float* __restrict__ a,
                                               const float* __restrict__ W,
                                               const float* __restrict__ dis,
                                               unsigned* __restrict__ h2b, int N) {
    __shared__ float sW[HID * EMB];
    __shared__ float sx[32][36];
    const int t = threadIdx.x;
    for (int i = t; i < HID * EMB; i += 256) sW[i] = W[i];
    const int row0 = blockIdx.x * 32;
    {
        const float4* av = (const float4*)(a + (size_t)row0 * HID);
        int r = t >> 3, c = t & 7;
        float4 v = make_float4(0.f, 0.f, 0.f, 0.f);
        if (row0 + r < N) v = av[(size_t)r * 8 + c];
        *(float4*)&sx[r][c * 4] = v;
    }
    __syncthreads();
    const int col4 = (t & 15) * 4;
    const int r0 = t >> 4;  // 0..15, also r0+16
    float a00 = 0.f, a01 = 0.f, a02 = 0.f, a03 = 0.f;
    float a10 = 0.f, a11 = 0.f, a12 = 0.f, a13 = 0.f;
#pragma unroll
    for (int k = 0; k < HID; ++k) {
        float4 w = *(const float4*)&sW[k * EMB + col4];
        float xa = sx[r0][k];
        float xb = sx[r0 + 16][k];
        a00 += xa * w.x; a01 += xa * w.y; a02 += xa * w.z; a03 += xa * w.w;
        a10 += xb * w.x; a11 += xb * w.y; a12 += xb * w.z; a13 += xb * w.w;
    }
    int ra = row0 + r0, rb = row0 + r0 + 16;
    int ju = (t & 15) * 2;  // uint index within row (32 uints/row)
    if (ra < N) {
        float d = dis[ra];
        unsigned u0 = bf16rne(a00 * d) | (bf16rne(a01 * d) << 16);
        unsigned u1 = bf16rne(a02 * d) | (bf16rne(a03 * d) << 16);
        *(uint2*)&h2b[(size_t)ra * 32 + ju] = make_uint2(u0, u1);
    }
    if (rb < N) {
        float d = dis[rb];
        unsigned u0 = bf16rne(a10 * d) | (bf16rne(a11 * d) << 16);
        unsigned u1 = bf16rne(a12 * d) | (bf16rne(a13 * d) << 16);
        *(uint2*)&h2b[(size_t)rb * 32 + ju] = make_uint2(u0, u1);
    }
}

// --- agg2: out = dis[i]*(h2b[i] + sum_in h2b[src]) + b2, 64 ch bf16-packed ---
// 8 lanes/node, uint4 (8 ch, 16B)/lane, degree loop unrolled x4
#define ACC8(v) \
    a0 += __uint_as_float((v).x << 16); a1 += __uint_as_float((v).x & 0xffff0000u); \
    a2 += __uint_as_float((v).y << 16); a3 += __uint_as_float((v).y & 0xffff0000u); \
    a4 += __uint_as_float((v).z << 16); a5 += __uint_as_float((v).z & 0xffff0000u); \
    a6 += __uint_as_float((v).w << 16); a7 += __uint_as_float((v).w & 0xffff0000u);

__global__ __launch_bounds__(256) void k_agg2(const unsigned* __restrict__ h2b,
                                              const int* __restrict__ roff,
                                              const int* __restrict__ csr,
                                              const float* __restrict__ dis,
                                              const float* __restrict__ b2,
                                              float* __restrict__ out, int N) {
    int t = blockIdx.x * 256 + threadIdx.x;
    int node = t >> 3;
    if (node >= N) return;
    int j = t & 7;
    const uint4* hb = (const uint4*)h2b;     // row stride 8 uint4 (128B)
    uint4 u = hb[(size_t)node * 8 + j];      // self-loop
    float a0, a1, a2, a3, a4, a5, a6, a7;
    a0 = __uint_as_float(u.x << 16); a1 = __uint_as_float(u.x & 0xffff0000u);
    a2 = __uint_as_float(u.y << 16); a3 = __uint_as_float(u.y & 0xffff0000u);
    a4 = __uint_as_float(u.z << 16); a5 = __uint_as_float(u.z & 0xffff0000u);
    a6 = __uint_as_float(u.w << 16); a7 = __uint_as_float(u.w & 0xffff0000u);
    int e0 = roff[node], e1 = roff[node + 1];
    int e = e0;
    for (; e + 4 <= e1; e += 4) {
        int s0 = __builtin_nontemporal_load(&csr[e + 0]);
        int s1 = __builtin_nontemporal_load(&csr[e + 1]);
        int s2 = __builtin_nontemporal_load(&csr[e + 2]);
        int s3 = __builtin_nontemporal_load(&csr[e + 3]);
        uint4 v0 = hb[(size_t)s0 * 8 + j];
        uint4 v1 = hb[(size_t)s1 * 8 + j];
        uint4 v2 = hb[(size_t)s2 * 8 + j];
        uint4 v3 = hb[(size_t)s3 * 8 + j];
        ACC8(v0) ACC8(v1) ACC8(v2) ACC8(v3)
    }
    for (; e < e1; ++e) {
        int s = __builtin_nontemporal_load(&csr[e]);
        uint4 v = hb[(size_t)s * 8 + j];
        ACC8(v)
    }
    float d = dis[node];
    float4 bb0 = *(const float4*)&b2[j * 8];
    float4 bb1 = *(const float4*)&b2[j * 8 + 4];
    vf4 o0, o1;
    o0.x = a0 * d + bb0.x; o0.y = a1 * d + bb0.y; o0.z = a2 * d + bb0.z; o0.w = a3 * d + bb0.w;
    o1.x = a4 * d + bb1.x; o1.y = a5 * d + bb1.y; o1.z = a6 * d + bb1.z; o1.w = a7 * d + bb1.w;
    float* op = &out[(size_t)node * EMB + j * 8];
    __builtin_nontemporal_store(o0, (vf4*)op);
    __builtin_nontemporal_store(o1, (vf4*)(op + 4));
}

extern "C" void kernel_launch(void* const* d_in, const int* in_sizes, int n_in,
                              void* d_out, int out_size, void* d_ws, size_t ws_size,
                              hipStream_t stream) {
    const float* x  = (const float*)d_in[0];
    const void*  ei = d_in[1];
    const float* W1 = (const float*)d_in[2];
    const float* b1 = (const float*)d_in[3];
    const float* W2 = (const float*)d_in[4];
    const float* b2 = (const float*)d_in[5];
    float* out = (float*)d_out;

    const int N = in_sizes[0] / NF;        // 100000
    const int E = in_sizes[1] / 2;         // 3200000
    const int nbuk = (N + 255) >> BSHIFT;  // 391

    char* ws = (char*)d_ws;
    size_t off = 0;
    auto take = [&](size_t bytes) -> void* {
        void* p = ws + off;
        off += (bytes + 255) & ~(size_t)255;
        return p;
    };
    // zeroed region first (single memset)
    int*   cnt    = (int*)take((size_t)N * 4);
    int*   bcur   = (int*)take((size_t)NBUKMAX * 4);
    int*   ovfcnt = (int*)take(4);
    int*   flag   = (int*)take(4);
    size_t zbytes = off;
    // rest
    int*                roff   = (int*)take((size_t)(N + 1) * 4);
    int*                cursor = (int*)take((size_t)N * 4);
    int*                bsum   = (int*)take(1024);
    float*              dis    = (float*)take((size_t)N * 4);
    unsigned long long* pairs  = (unsigned long long*)take((size_t)nbuk * CAP * 8);
    unsigned long long* ovf    = (unsigned long long*)take((size_t)OVFCAP * 8);
    int*                csr    = (int*)take((size_t)E * 4);
    float*              h1s    = (float*)take((size_t)N * HID * 4);
    float*              out1   = (float*)take((size_t)N * HID * 4);
    unsigned*           h2b    = (unsigned*)take((size_t)N * EMB * 2);

    (void)hipMemsetAsync(cnt, 0, zbytes, stream);

    const int NB1024 = (N + 1023) / 1024;  // 98 (<=128 for scan_p2)

    k_detect<<<16, 256, 0, stream>>>((const unsigned*)ei, flag);
    k_part<<<(E + TILE - 1) / TILE, 256, 0, stream>>>(ei, flag, pairs, bcur, cnt,
                                                      ovf, ovfcnt, E, nbuk);
    k_scan_p1<<<NB1024, 256, 0, stream>>>(cnt, bsum, N);
    k_scan_p2<<<1, 128, 0, stream>>>(bsum, NB1024);
    k_scan_p3<<<NB1024, 256, 0, stream>>>(cnt, bsum, roff, cursor, dis, N, E);
    k_scat<<<nbuk, 256, 0, stream>>>(pairs, bcur, cursor, csr);
    k_ovf<<<8, 256, 0, stream>>>(ovf, ovfcnt, cursor, csr);

    k_gemm1<<<(N + 31) / 32, 256, 0, stream>>>(x, W1, dis, h1s, N);
    k_agg1<<<((size_t)N * 8 + 255) / 256, 256, 0, stream>>>(h1s, roff, csr, dis, b1, out1, N);
    k_gemm2<<<(N + 31) / 32, 256, 0, stream>>>(out1, W2, dis, h2b, N);
    k_agg2<<<((size_t)N * 8 + 255) / 256, 256, 0, stream>>>(h2b, roff, csr, dis, b2, out, N);
}

// Round 5
// 280.699 us; speedup vs baseline: 3.1208x; 1.7533x over previous
//
#include <hip/hip_runtime.h>
#include <hip/hip_bf16.h>

// ---------------------------------------------------------------------------
// 2-layer GCN (PyG GCNConv) N=100000, E=3.2M.
// Pipeline: bucket-sort edges by dst (98 buckets x 1024 nodes, u32 entries),
// per-bucket CSR build (LDS hist + scan, L2-resident scatter), then:
//   h1b = bf16(dis*(x@W1))                  [N x 32 bf16]
//   t   = bf16(dis*relu(dis*agg(h1b)+b1))   [N x 32 bf16]  (next dis folded)
//   s2  = dis*agg(t)                        [N x 32 fp32]
//   out = s2@W2 + b2                        [N x 64 fp32]
// (layer-2 aggregation moved before the W2 GEMM -- GCNConv is linear)
// ---------------------------------------------------------------------------

#define NF 128
#define HID 32
#define EMB 64

#define BSHIFT 10
#define BNODES 1024                       // nodes per bucket
#define CAP 36864                         // mean 32653 + ~23 sigma
#define NBUKMAX 128                       // >= ceil(100000/1024)=98
#define TILE 4096
#define EPT 16

typedef float vf4 __attribute__((ext_vector_type(4)));

static __device__ __forceinline__ unsigned bf16rne(float f) {
    unsigned u = __float_as_uint(f);
    return (u + 0x7fffu + ((u >> 16) & 1u)) >> 16;
}

// unpack-accumulate 8 bf16 channels from a uint4
#define ACC8(v) \
    a0 += __uint_as_float((v).x << 16); a1 += __uint_as_float((v).x & 0xffff0000u); \
    a2 += __uint_as_float((v).y << 16); a3 += __uint_as_float((v).y & 0xffff0000u); \
    a4 += __uint_as_float((v).z << 16); a5 += __uint_as_float((v).z & 0xffff0000u); \
    a6 += __uint_as_float((v).w << 16); a7 += __uint_as_float((v).w & 0xffff0000u);

// --- edge dtype detection: flag=0 -> int64, flag=1 -> int32 ---
__global__ void k_detect(const unsigned* __restrict__ raw, int* __restrict__ flag) {
    int t = blockIdx.x * blockDim.x + threadIdx.x;   // 4096 threads
    unsigned w = raw[2 * t + 1];                     // high word if int64
    if (w != 0u) atomicOr(flag, 1);
}

// --- multisplit edges into 1024-node dst-buckets (u32 entries) ---
__global__ __launch_bounds__(256) void k_part(const void* __restrict__ ei,
                                              const int* __restrict__ flag,
                                              unsigned* __restrict__ pairs,
                                              int* __restrict__ bcur,
                                              int* __restrict__ cnt_ovf,
                                              unsigned long long* __restrict__ ovf,
                                              int* __restrict__ ovfcnt,
                                              int E, int nbuk) {
    __shared__ unsigned sEnt[TILE];            // 16 KB
    __shared__ unsigned char sB[TILE];         // 4 KB
    __shared__ int hcnt[NBUKMAX], lstart[NBUKMAX], gbase[NBUKMAX], lcur[NBUKMAX];
    const int tid = threadIdx.x;
    const int tile0 = blockIdx.x * TILE;
    if (tile0 >= E) return;
    const int tcnt = min(TILE, E - tile0);
    const bool is64 = (*flag == 0);

    for (int b = tid; b < nbuk; b += 256) { hcnt[b] = 0; lcur[b] = 0; }
    __syncthreads();

    int ms[EPT], md[EPT];
#pragma unroll
    for (int k = 0; k < EPT; ++k) {
        int i = tile0 + k * 256 + tid;
        ms[k] = -1;
        if (i < tile0 + tcnt) {
            int s, d;
            if (is64) {
                const long long* p = (const long long*)ei;
                s = (int)__builtin_nontemporal_load(&p[i]);
                d = (int)__builtin_nontemporal_load(&p[(size_t)E + i]);
            } else {
                const int* p = (const int*)ei;
                s = __builtin_nontemporal_load(&p[i]);
                d = __builtin_nontemporal_load(&p[E + i]);
            }
            ms[k] = s; md[k] = d;
            atomicAdd(&hcnt[d >> BSHIFT], 1);
        }
    }
    __syncthreads();

    if (tid < 64) {  // wave 0: scan bucket counts (2 contiguous per lane), reserve
        int i0 = tid * 2, i1 = tid * 2 + 1;
        int c0 = (i0 < nbuk) ? hcnt[i0] : 0;
        int c1 = (i1 < nbuk) ? hcnt[i1] : 0;
        int run = c0 + c1, inc = run;
#pragma unroll
        for (int off = 1; off < 64; off <<= 1) {
            int t2 = __shfl_up(inc, off);
            if (tid >= off) inc += t2;
        }
        int excl = inc - run;
        if (i0 < nbuk) { lstart[i0] = excl;      gbase[i0] = c0 ? atomicAdd(&bcur[i0], c0) : 0; }
        if (i1 < nbuk) { lstart[i1] = excl + c0; gbase[i1] = c1 ? atomicAdd(&bcur[i1], c1) : 0; }
    }
    __syncthreads();

#pragma unroll
    for (int k = 0; k < EPT; ++k) {
        if (ms[k] >= 0) {
            int b = md[k] >> BSHIFT;
            int c = atomicAdd(&lcur[b], 1);
            int slot = lstart[b] + c;
            sEnt[slot] = ((unsigned)(md[k] & (BNODES - 1)) << 17) | (unsigned)ms[k];
            sB[slot] = (unsigned char)b;
        }
    }
    __syncthreads();

    for (int j = tid; j < tcnt; j += 256) {   // bucket-ordered flush (L2 merges lines)
        unsigned ent = sEnt[j];
        int b = sB[j];
        int g = gbase[b] + (j - lstart[b]);
        if (g < CAP) {
            pairs[(size_t)b * CAP + g] = ent;
        } else {
            int d = (b << BSHIFT) | (int)(ent >> 17);
            int s = (int)(ent & 0x1FFFFu);
            int o = atomicAdd(ovfcnt, 1);
            ovf[o] = ((unsigned long long)(unsigned)d << 32) | (unsigned)s;
            atomicAdd(&cnt_ovf[d], 1);
        }
    }
}

// --- exclusive scan of bucket totals -> bucket CSR bases ---
__global__ void k_bscan(const int* __restrict__ bcur, int* __restrict__ bbase,
                        int* __restrict__ roff, int nbuk, int E, int N) {
    __shared__ int sh[128];
    int t = threadIdx.x;  // blockDim=128, nbuk<=128
    int v = (t < nbuk) ? bcur[t] : 0;
    sh[t] = v;
    __syncthreads();
    for (int off = 1; off < 128; off <<= 1) {
        int add = (t >= off) ? sh[t - off] : 0;
        __syncthreads();
        sh[t] += add;
        __syncthreads();
    }
    if (t < nbuk) bbase[t] = sh[t] - v;
    if (t == 0) roff[N] = E;
}

// --- per-bucket CSR build: hist -> scan -> roff/dis/cursor -> scatter ---
__global__ __launch_bounds__(256) void k_scat(const unsigned* __restrict__ pairs,
                                              const int* __restrict__ bcur,
                                              const int* __restrict__ bbase,
                                              const int* __restrict__ cnt_ovf,
                                              int* __restrict__ roff,
                                              int* __restrict__ cursor,
                                              float* __restrict__ dis,
                                              int* __restrict__ csr, int N) {
    __shared__ int hist[BNODES];   // becomes excl after scan
    __shared__ int lc[BNODES];
    __shared__ int part[256];
    const int b = blockIdx.x, tid = threadIdx.x;
    const int nb = min(bcur[b], CAP);
    const int base = bbase[b];
    const unsigned* pp = pairs + (size_t)b * CAP;

    for (int i = tid; i < BNODES; i += 256) { hist[i] = 0; lc[i] = 0; }
    __syncthreads();
    for (int i = tid; i < nb; i += 256) atomicAdd(&hist[pp[i] >> 17], 1);
    __syncthreads();

    int h[4], tv[4], run = 0;
    const int node0 = (b << BSHIFT) + tid * 4;
#pragma unroll
    for (int k = 0; k < 4; ++k) {
        int l = tid * 4 + k;
        h[k] = hist[l];
        int node = node0 + k;
        int ov = (node < N) ? cnt_ovf[node] : 0;
        tv[k] = h[k] + ov;
        run += tv[k];
    }
    part[tid] = run;
    __syncthreads();
    for (int off = 1; off < 256; off <<= 1) {
        int add = (tid >= off) ? part[tid - off] : 0;
        __syncthreads();
        part[tid] += add;
        __syncthreads();
    }
    int excl = part[tid] - run;
#pragma unroll
    for (int k = 0; k < 4; ++k) {
        int l = tid * 4 + k;
        int node = node0 + k;
        hist[l] = excl;
        if (node < N) {
            roff[node] = base + excl;
            cursor[node] = base + excl + h[k];      // overflow entries go after staged
            dis[node] = rsqrtf((float)(tv[k] + 1)); // deg includes self-loop
        }
        excl += tv[k];
    }
    __syncthreads();
    for (int i = tid; i < nb; i += 256) {
        unsigned ent = pp[i];                       // L2-hot second read
        int l = ent >> 17;
        int pos = base + hist[l] + atomicAdd(&lc[l], 1);
        csr[pos] = (int)(ent & 0x1FFFFu);           // scatter within L2-resident region
    }
}

// --- overflow sweep (empty for benchmark data) ---
__global__ __launch_bounds__(256) void k_ovf(const unsigned long long* __restrict__ ovf,
                                             const int* __restrict__ ovfcnt,
                                             int* __restrict__ cursor,
                                             int* __restrict__ csr) {
    int n = *ovfcnt;
    for (int i = blockIdx.x * 256 + threadIdx.x; i < n; i += 256 * 8) {
        unsigned long long pr = ovf[i];
        int pos = atomicAdd(&cursor[(int)(unsigned)(pr >> 32)], 1);
        csr[pos] = (int)(unsigned)pr;
    }
}

// --- GEMM1: h1b[r] = bf16(dis[r] * (x[r] @ W1)), x: N x 128, W1: 128 x 32 ---
__global__ __launch_bounds__(256) void k_gemm1(const float* __restrict__ x,
                                               const float* __restrict__ W,
                                               const float* __restrict__ dis,
                                               unsigned* __restrict__ h1b, int N) {
    __shared__ float sW[NF * HID];     // 16 KB
    __shared__ float sx[32][132];
    const int t = threadIdx.x;
    for (int i = t; i < NF * HID; i += 256) sW[i] = W[i];
    const int row0 = blockIdx.x * 32;
    {
        const float4* xv = (const float4*)(x + (size_t)row0 * NF);
        for (int i = t; i < 32 * 32; i += 256) {
            int r = i >> 5, c = i & 31;
            float4 v = make_float4(0.f, 0.f, 0.f, 0.f);
            if (row0 + r < N) v = xv[(size_t)r * 32 + c];
            *(float4*)&sx[r][c * 4] = v;
        }
    }
    __syncthreads();
    const int col4 = (t & 7) * 4;
    const int row = t >> 3;
    float a0 = 0.f, a1 = 0.f, a2 = 0.f, a3 = 0.f;
#pragma unroll 8
    for (int k = 0; k < NF; ++k) {
        float xs = sx[row][k];
        float4 w = *(const float4*)&sW[k * HID + col4];
        a0 += xs * w.x; a1 += xs * w.y; a2 += xs * w.z; a3 += xs * w.w;
    }
    int r = row0 + row;
    if (r < N) {
        float d = dis[r];
        unsigned u0 = bf16rne(a0 * d) | (bf16rne(a1 * d) << 16);
        unsigned u1 = bf16rne(a2 * d) | (bf16rne(a3 * d) << 16);
        *(uint2*)&h1b[(size_t)r * 16 + (t & 7) * 2] = make_uint2(u0, u1);
    }
}

// --- agg1: t = bf16(dis * relu(dis*(self+sum) + b1)); 32 ch bf16, 4 lanes/node ---
__global__ __launch_bounds__(256) void k_agg1(const uint4* __restrict__ h1b,
                                              const int* __restrict__ roff,
                                              const int* __restrict__ csr,
                                              const float* __restrict__ dis,
                                              const float* __restrict__ b1,
                                              uint4* __restrict__ t_out, int N) {
    int tt = blockIdx.x * 256 + threadIdx.x;
    int node = tt >> 2;
    if (node >= N) return;
    int j = tt & 3;
    uint4 u = h1b[(size_t)node * 4 + j];        // self-loop
    float a0, a1, a2, a3, a4, a5, a6, a7;
    a0 = __uint_as_float(u.x << 16); a1 = __uint_as_float(u.x & 0xffff0000u);
    a2 = __uint_as_float(u.y << 16); a3 = __uint_as_float(u.y & 0xffff0000u);
    a4 = __uint_as_float(u.z << 16); a5 = __uint_as_float(u.z & 0xffff0000u);
    a6 = __uint_as_float(u.w << 16); a7 = __uint_as_float(u.w & 0xffff0000u);
    int e0 = roff[node], e1 = roff[node + 1];
    int e = e0;
    for (; e + 4 <= e1; e += 4) {
        int s0 = __builtin_nontemporal_load(&csr[e + 0]);
        int s1 = __builtin_nontemporal_load(&csr[e + 1]);
        int s2 = __builtin_nontemporal_load(&csr[e + 2]);
        int s3 = __builtin_nontemporal_load(&csr[e + 3]);
        uint4 v0 = h1b[(size_t)s0 * 4 + j];
        uint4 v1 = h1b[(size_t)s1 * 4 + j];
        uint4 v2 = h1b[(size_t)s2 * 4 + j];
        uint4 v3 = h1b[(size_t)s3 * 4 + j];
        ACC8(v0) ACC8(v1) ACC8(v2) ACC8(v3)
    }
    for (; e < e1; ++e) {
        int s = __builtin_nontemporal_load(&csr[e]);
        uint4 v = h1b[(size_t)s * 4 + j];
        ACC8(v)
    }
    float d = dis[node];
    float4 bb0 = *(const float4*)&b1[j * 8];
    float4 bb1 = *(const float4*)&b1[j * 8 + 4];
    float r0 = fmaxf(a0 * d + bb0.x, 0.f) * d, r1 = fmaxf(a1 * d + bb0.y, 0.f) * d;
    float r2 = fmaxf(a2 * d + bb0.z, 0.f) * d, r3 = fmaxf(a3 * d + bb0.w, 0.f) * d;
    float r4 = fmaxf(a4 * d + bb1.x, 0.f) * d, r5 = fmaxf(a5 * d + bb1.y, 0.f) * d;
    float r6 = fmaxf(a6 * d + bb1.z, 0.f) * d, r7 = fmaxf(a7 * d + bb1.w, 0.f) * d;
    uint4 o;
    o.x = bf16rne(r0) | (bf16rne(r1) << 16);
    o.y = bf16rne(r2) | (bf16rne(r3) << 16);
    o.z = bf16rne(r4) | (bf16rne(r5) << 16);
    o.w = bf16rne(r6) | (bf16rne(r7) << 16);
    t_out[(size_t)node * 4 + j] = o;
}

// --- agg2: s2 = dis*(self + sum t[src]); 32 ch fp32 out, 4 lanes/node ---
__global__ __launch_bounds__(256) void k_agg2(const uint4* __restrict__ tb,
                                              const int* __restrict__ roff,
                                              const int* __restrict__ csr,
                                              const float* __restrict__ dis,
                                              float* __restrict__ s2, int N) {
    int tt = blockIdx.x * 256 + threadIdx.x;
    int node = tt >> 2;
    if (node >= N) return;
    int j = tt & 3;
    uint4 u = tb[(size_t)node * 4 + j];         // self-loop
    float a0, a1, a2, a3, a4, a5, a6, a7;
    a0 = __uint_as_float(u.x << 16); a1 = __uint_as_float(u.x & 0xffff0000u);
    a2 = __uint_as_float(u.y << 16); a3 = __uint_as_float(u.y & 0xffff0000u);
    a4 = __uint_as_float(u.z << 16); a5 = __uint_as_float(u.z & 0xffff0000u);
    a6 = __uint_as_float(u.w << 16); a7 = __uint_as_float(u.w & 0xffff0000u);
    int e0 = roff[node], e1 = roff[node + 1];
    int e = e0;
    for (; e + 4 <= e1; e += 4) {
        int s0 = __builtin_nontemporal_load(&csr[e + 0]);
        int s1 = __builtin_nontemporal_load(&csr[e + 1]);
        int s2i = __builtin_nontemporal_load(&csr[e + 2]);
        int s3 = __builtin_nontemporal_load(&csr[e + 3]);
        uint4 v0 = tb[(size_t)s0 * 4 + j];
        uint4 v1 = tb[(size_t)s1 * 4 + j];
        uint4 v2 = tb[(size_t)s2i * 4 + j];
        uint4 v3 = tb[(size_t)s3 * 4 + j];
        ACC8(v0) ACC8(v1) ACC8(v2) ACC8(v3)
    }
    for (; e < e1; ++e) {
        int s = __builtin_nontemporal_load(&csr[e]);
        uint4 v = tb[(size_t)s * 4 + j];
        ACC8(v)
    }
    float d = dis[node];
    float* op = &s2[(size_t)node * HID + j * 8];
    *(float4*)op       = make_float4(a0 * d, a1 * d, a2 * d, a3 * d);
    *(float4*)(op + 4) = make_float4(a4 * d, a5 * d, a6 * d, a7 * d);
}

// --- GEMM2: out[r] = s2[r] @ W2 + b2, s2: N x 32, W2: 32 x 64 ---
__global__ __launch_bounds__(256) void k_gemm2(const float* __restrict__ a,
                                               const float* __restrict__ W,
                                               const float* __restrict__ b2,
                                               float* __restrict__ out, int N) {
    __shared__ float sW[HID * EMB];
    __shared__ float sx[32][36];
    const int t = threadIdx.x;
    for (int i = t; i < HID * EMB; i += 256) sW[i] = W[i];
    const int row0 = blockIdx.x * 32;
    {
        const float4* av = (const float4*)(a + (size_t)row0 * HID);
        int r = t >> 3, c = t & 7;
        float4 v = make_float4(0.f, 0.f, 0.f, 0.f);
        if (row0 + r < N) v = av[(size_t)r * 8 + c];
        *(float4*)&sx[r][c * 4] = v;
    }
    __syncthreads();
    const int col4 = (t & 15) * 4;
    const int r0 = t >> 4;  // 0..15, also r0+16
    float a00 = 0.f, a01 = 0.f, a02 = 0.f, a03 = 0.f;
    float a10 = 0.f, a11 = 0.f, a12 = 0.f, a13 = 0.f;
#pragma unroll
    for (int k = 0; k < HID; ++k) {
        float4 w = *(const float4*)&sW[k * EMB + col4];
        float xa = sx[r0][k];
        float xb = sx[r0 + 16][k];
        a00 += xa * w.x; a01 += xa * w.y; a02 += xa * w.z; a03 += xa * w.w;
        a10 += xb * w.x; a11 += xb * w.y; a12 += xb * w.z; a13 += xb * w.w;
    }
    float4 bb = *(const float4*)&b2[col4];
    int ra = row0 + r0, rb = row0 + r0 + 16;
    if (ra < N) {
        vf4 o; o.x = a00 + bb.x; o.y = a01 + bb.y; o.z = a02 + bb.z; o.w = a03 + bb.w;
        __builtin_nontemporal_store(o, (vf4*)&out[(size_t)ra * EMB + col4]);
    }
    if (rb < N) {
        vf4 o; o.x = a10 + bb.x; o.y = a11 + bb.y; o.z = a12 + bb.z; o.w = a13 + bb.w;
        __builtin_nontemporal_store(o, (vf4*)&out[(size_t)rb * EMB + col4]);
    }
}

extern "C" void kernel_launch(void* const* d_in, const int* in_sizes, int n_in,
                              void* d_out, int out_size, void* d_ws, size_t ws_size,
                              hipStream_t stream) {
    const float* x  = (const float*)d_in[0];
    const void*  ei = d_in[1];
    const float* W1 = (const float*)d_in[2];
    const float* b1 = (const float*)d_in[3];
    const float* W2 = (const float*)d_in[4];
    const float* b2 = (const float*)d_in[5];
    float* out = (float*)d_out;

    const int N = in_sizes[0] / NF;              // 100000
    const int E = in_sizes[1] / 2;               // 3200000
    const int nbuk = (N + BNODES - 1) >> BSHIFT; // 98

    char* ws = (char*)d_ws;
    size_t off = 0;
    auto take = [&](size_t bytes) -> void* {
        void* p = ws + off;
        off += (bytes + 255) & ~(size_t)255;
        return p;
    };
    // zeroed region first (single memset)
    int* cnt_ovf = (int*)take((size_t)N * 4);
    int* bcur    = (int*)take((size_t)NBUKMAX * 4);
    int* ovfcnt  = (int*)take(4);
    int* flag    = (int*)take(4);
    size_t zbytes = off;
    // rest
    int*                bbase  = (int*)take((size_t)NBUKMAX * 4);
    int*                roff   = (int*)take((size_t)(N + 1) * 4);
    int*                cursor = (int*)take((size_t)N * 4);
    float*              dis    = (float*)take((size_t)N * 4);
    unsigned*           pairs  = (unsigned*)take((size_t)nbuk * CAP * 4);
    unsigned long long* ovf    = (unsigned long long*)take((size_t)E * 8);
    int*                csr    = (int*)take((size_t)E * 4);
    unsigned*           h1b    = (unsigned*)take((size_t)N * HID * 2);
    unsigned*           tb     = (unsigned*)take((size_t)N * HID * 2);
    float*              s2     = (float*)take((size_t)N * HID * 4);

    (void)hipMemsetAsync(cnt_ovf, 0, zbytes, stream);

    k_detect<<<16, 256, 0, stream>>>((const unsigned*)ei, flag);
    k_part<<<(E + TILE - 1) / TILE, 256, 0, stream>>>(ei, flag, pairs, bcur, cnt_ovf,
                                                      ovf, ovfcnt, E, nbuk);
    k_bscan<<<1, 128, 0, stream>>>(bcur, bbase, roff, nbuk, E, N);
    k_scat<<<nbuk, 256, 0, stream>>>(pairs, bcur, bbase, cnt_ovf, roff, cursor, dis, csr, N);
    k_ovf<<<8, 256, 0, stream>>>(ovf, ovfcnt, cursor, csr);

    k_gemm1<<<(N + 31) / 32, 256, 0, stream>>>(x, W1, dis, h1b, N);
    k_agg1<<<((size_t)N * 4 + 255) / 256, 256, 0, stream>>>((const uint4*)h1b, roff, csr,
                                                            dis, b1, (uint4*)tb, N);
    k_agg2<<<((size_t)N * 4 + 255) / 256, 256, 0, stream>>>((const uint4*)tb, roff, csr,
                                                            dis, s2, N);
    k_gemm2<<<(N + 31) / 32, 256, 0, stream>>>(s2, W2, b2, out, N);
}

// Round 6
// 252.454 us; speedup vs baseline: 3.4699x; 1.1119x over previous
//
#include <hip/hip_runtime.h>
#include <hip/hip_bf16.h>

// ---------------------------------------------------------------------------
// 2-layer GCN (PyG GCNConv) N=100000, E=3.2M.
// Pipeline: bucket-sort edges by dst (98 buckets x 1024 nodes, u32 entries),
// 3-phase parallel CSR build (per-chunk hist -> per-bucket scan -> per-chunk
// scatter, XCD-colocated chunks), then:
//   h1b = bf16(dis*(x@W1))                  [N x 32 bf16]
//   t   = bf16(dis*relu(dis*agg(h1b)+b1))   [N x 32 bf16]  (next dis folded)
//   s2  = dis*agg(t)                        [N x 32 fp32]
//   out = s2@W2 + b2                        [N x 64 fp32]
// ---------------------------------------------------------------------------

#define NF 128
#define HID 32
#define EMB 64

#define BSHIFT 10
#define BNODES 1024                       // nodes per bucket
#define CAP 36864                         // mean 32653 + ~23 sigma
#define NBUKMAX 128                       // >= ceil(100000/1024)=98
#define TILE 4096
#define EPT 16
#define CHUNKS 8                          // scatter chunks per bucket

typedef float vf4 __attribute__((ext_vector_type(4)));

static __device__ __forceinline__ unsigned bf16rne(float f) {
    unsigned u = __float_as_uint(f);
    return (u + 0x7fffu + ((u >> 16) & 1u)) >> 16;
}

// swizzled slot id: all CHUNKS chunks of bucket b share idx%8 == b%8 (same XCD
// under round-robin dispatch heuristic; perf-only, correctness-independent)
static __device__ __host__ __forceinline__ int hslot(int b, int c) {
    return ((b >> 3) << 6) | (c << 3) | (b & 7);
}

// unpack-accumulate 8 bf16 channels from a uint4
#define ACC8(v) \
    a0 += __uint_as_float((v).x << 16); a1 += __uint_as_float((v).x & 0xffff0000u); \
    a2 += __uint_as_float((v).y << 16); a3 += __uint_as_float((v).y & 0xffff0000u); \
    a4 += __uint_as_float((v).z << 16); a5 += __uint_as_float((v).z & 0xffff0000u); \
    a6 += __uint_as_float((v).w << 16); a7 += __uint_as_float((v).w & 0xffff0000u);

// --- edge dtype detection: flag=0 -> int64, flag=1 -> int32 ---
__global__ void k_detect(const unsigned* __restrict__ raw, int* __restrict__ flag) {
    int t = blockIdx.x * blockDim.x + threadIdx.x;   // 4096 threads
    unsigned w = raw[2 * t + 1];                     // high word if int64
    if (w != 0u) atomicOr(flag, 1);
}

// --- multisplit edges into 1024-node dst-buckets (u32 entries) ---
__global__ __launch_bounds__(256) void k_part(const void* __restrict__ ei,
                                              const int* __restrict__ flag,
                                              unsigned* __restrict__ pairs,
                                              int* __restrict__ bcur,
                                              int* __restrict__ cnt_ovf,
                                              unsigned long long* __restrict__ ovf,
                                              int* __restrict__ ovfcnt,
                                              int E, int nbuk) {
    __shared__ unsigned sEnt[TILE];            // 16 KB
    __shared__ unsigned char sB[TILE];         // 4 KB
    __shared__ int hcnt[NBUKMAX], lstart[NBUKMAX], gbase[NBUKMAX], lcur[NBUKMAX];
    const int tid = threadIdx.x;
    const int tile0 = blockIdx.x * TILE;
    if (tile0 >= E) return;
    const int tcnt = min(TILE, E - tile0);
    const bool is64 = (*flag == 0);

    for (int b = tid; b < nbuk; b += 256) { hcnt[b] = 0; lcur[b] = 0; }
    __syncthreads();

    int ms[EPT], md[EPT];
#pragma unroll
    for (int k = 0; k < EPT; ++k) {
        int i = tile0 + k * 256 + tid;
        ms[k] = -1;
        if (i < tile0 + tcnt) {
            int s, d;
            if (is64) {
                const long long* p = (const long long*)ei;
                s = (int)__builtin_nontemporal_load(&p[i]);
                d = (int)__builtin_nontemporal_load(&p[(size_t)E + i]);
            } else {
                const int* p = (const int*)ei;
                s = __builtin_nontemporal_load(&p[i]);
                d = __builtin_nontemporal_load(&p[E + i]);
            }
            ms[k] = s; md[k] = d;
            atomicAdd(&hcnt[d >> BSHIFT], 1);
        }
    }
    __syncthreads();

    if (tid < 64) {  // wave 0: scan bucket counts (2 contiguous per lane), reserve
        int i0 = tid * 2, i1 = tid * 2 + 1;
        int c0 = (i0 < nbuk) ? hcnt[i0] : 0;
        int c1 = (i1 < nbuk) ? hcnt[i1] : 0;
        int run = c0 + c1, inc = run;
#pragma unroll
        for (int off = 1; off < 64; off <<= 1) {
            int t2 = __shfl_up(inc, off);
            if (tid >= off) inc += t2;
        }
        int excl = inc - run;
        if (i0 < nbuk) { lstart[i0] = excl;      gbase[i0] = c0 ? atomicAdd(&bcur[i0], c0) : 0; }
        if (i1 < nbuk) { lstart[i1] = excl + c0; gbase[i1] = c1 ? atomicAdd(&bcur[i1], c1) : 0; }
    }
    __syncthreads();

#pragma unroll
    for (int k = 0; k < EPT; ++k) {
        if (ms[k] >= 0) {
            int b = md[k] >> BSHIFT;
            int c = atomicAdd(&lcur[b], 1);
            int slot = lstart[b] + c;
            sEnt[slot] = ((unsigned)(md[k] & (BNODES - 1)) << 17) | (unsigned)ms[k];
            sB[slot] = (unsigned char)b;
        }
    }
    __syncthreads();

    for (int j = tid; j < tcnt; j += 256) {   // bucket-ordered flush (L2 merges lines)
        unsigned ent = sEnt[j];
        int b = sB[j];
        int g = gbase[b] + (j - lstart[b]);
        if (g < CAP) {
            pairs[(size_t)b * CAP + g] = ent;
        } else {
            int d = (b << BSHIFT) | (int)(ent >> 17);
            int s = (int)(ent & 0x1FFFFu);
            int o = atomicAdd(ovfcnt, 1);
            ovf[o] = ((unsigned long long)(unsigned)d << 32) | (unsigned)s;
            atomicAdd(&cnt_ovf[d], 1);
        }
    }
}

// --- exclusive scan of bucket totals -> bucket CSR bases ---
__global__ void k_bscan(const int* __restrict__ bcur, int* __restrict__ bbase,
                        int* __restrict__ roff, int nbuk, int E, int N) {
    __shared__ int sh[128];
    int t = threadIdx.x;  // blockDim=128, nbuk<=128
    int v = (t < nbuk) ? bcur[t] : 0;
    sh[t] = v;
    __syncthreads();
    for (int off = 1; off < 128; off <<= 1) {
        int add = (t >= off) ? sh[t - off] : 0;
        __syncthreads();
        sh[t] += add;
        __syncthreads();
    }
    if (t < nbuk) bbase[t] = sh[t] - v;
    if (t == 0) roff[N] = E;
}

// --- phase A: per-chunk LDS histogram -> histc[slot][1024] ---
__global__ __launch_bounds__(256) void k_hist(const unsigned* __restrict__ pairs,
                                              const int* __restrict__ bcur,
                                              int* __restrict__ histc, int nbuk) {
    __shared__ int hist[BNODES];
    const int idx = blockIdx.x;
    const int c = (idx >> 3) & 7;
    const int b = (idx & 7) | ((idx >> 6) << 3);
    if (b >= nbuk) return;
    const int tid = threadIdx.x;
    const int nb = min(bcur[b], CAP);
    const int csz = (nb + CHUNKS - 1) / CHUNKS;
    const int i0 = c * csz, i1 = min(nb, i0 + csz);
    const unsigned* pp = pairs + (size_t)b * CAP;
    for (int i = tid; i < BNODES; i += 256) hist[i] = 0;
    __syncthreads();
    for (int i = i0 + tid; i < i1; i += 256)
        atomicAdd(&hist[__builtin_nontemporal_load(&pp[i]) >> 17], 1);
    __syncthreads();
    int* out = histc + ((size_t)idx << 10);
    for (int i = tid; i < BNODES; i += 256) out[i] = hist[i];
}

// --- phase B: per-bucket node scan -> roff/cursor/dis + chunk bases in histc ---
__global__ __launch_bounds__(256) void k_nscan(int* __restrict__ histc,
                                               const int* __restrict__ bbase,
                                               const int* __restrict__ cnt_ovf,
                                               int* __restrict__ roff,
                                               int* __restrict__ cursor,
                                               float* __restrict__ dis, int N) {
    __shared__ int part[256];
    const int b = blockIdx.x, tid = threadIdx.x;
    const int base = bbase[b];
    int h[4][CHUNKS], stg[4], tv[4];
    int run = 0;
    const int l0 = tid * 4;
#pragma unroll
    for (int k = 0; k < 4; ++k) {
        int l = l0 + k;
        int node = (b << BSHIFT) + l;
        int st = 0;
#pragma unroll
        for (int c = 0; c < CHUNKS; ++c) {
            h[k][c] = histc[((size_t)hslot(b, c) << 10) + l];
            st += h[k][c];
        }
        stg[k] = st;
        int ov = (node < N) ? cnt_ovf[node] : 0;
        tv[k] = st + ov;
        run += tv[k];
    }
    part[tid] = run;
    __syncthreads();
    for (int off = 1; off < 256; off <<= 1) {
        int add = (tid >= off) ? part[tid - off] : 0;
        __syncthreads();
        part[tid] += add;
        __syncthreads();
    }
    int excl = part[tid] - run;
#pragma unroll
    for (int k = 0; k < 4; ++k) {
        int l = l0 + k;
        int node = (b << BSHIFT) + l;
        if (node < N) {
            roff[node] = base + excl;
            cursor[node] = base + excl + stg[k];     // overflow appended after staged
            dis[node] = rsqrtf((float)(tv[k] + 1));  // deg includes self-loop
        }
        int cb = base + excl;
#pragma unroll
        for (int c = 0; c < CHUNKS; ++c) {           // in-place: hist -> chunk base
            int hh = h[k][c];
            histc[((size_t)hslot(b, c) << 10) + l] = cb;
            cb += hh;
        }
        excl += tv[k];
    }
}

// --- phase C: per-chunk scatter into CSR using chunk bases ---
__global__ __launch_bounds__(256) void k_scat2(const unsigned* __restrict__ pairs,
                                               const int* __restrict__ bcur,
                                               const int* __restrict__ histc,
                                               int* __restrict__ csr, int nbuk) {
    __shared__ int cbase[BNODES];
    __shared__ int lc[BNODES];
    const int idx = blockIdx.x;
    const int c = (idx >> 3) & 7;
    const int b = (idx & 7) | ((idx >> 6) << 3);
    if (b >= nbuk) return;
    const int tid = threadIdx.x;
    const int nb = min(bcur[b], CAP);
    const int csz = (nb + CHUNKS - 1) / CHUNKS;
    const int i0 = c * csz, i1 = min(nb, i0 + csz);
    const unsigned* pp = pairs + (size_t)b * CAP;
    const int* hc = histc + ((size_t)idx << 10);
    for (int i = tid; i < BNODES; i += 256) { cbase[i] = hc[i]; lc[i] = 0; }
    __syncthreads();
    for (int i = i0 + tid; i < i1; i += 256) {
        unsigned ent = pp[i];
        int l = ent >> 17;
        int pos = cbase[l] + atomicAdd(&lc[l], 1);
        csr[pos] = (int)(ent & 0x1FFFFu);
    }
}

// --- overflow sweep (empty for benchmark data) ---
__global__ __launch_bounds__(256) void k_ovf(const unsigned long long* __restrict__ ovf,
                                             const int* __restrict__ ovfcnt,
                                             int* __restrict__ cursor,
                                             int* __restrict__ csr) {
    int n = *ovfcnt;
    for (int i = blockIdx.x * 256 + threadIdx.x; i < n; i += 256 * 8) {
        unsigned long long pr = ovf[i];
        int pos = atomicAdd(&cursor[(int)(unsigned)(pr >> 32)], 1);
        csr[pos] = (int)(unsigned)pr;
    }
}

// --- GEMM1: h1b[r] = bf16(dis[r] * (x[r] @ W1)), x: N x 128, W1: 128 x 32 ---
__global__ __launch_bounds__(256) void k_gemm1(const float* __restrict__ x,
                                               const float* __restrict__ W,
                                               const float* __restrict__ dis,
                                               unsigned* __restrict__ h1b, int N) {
    __shared__ float sW[NF * HID];     // 16 KB
    __shared__ float sx[32][132];
    const int t = threadIdx.x;
    for (int i = t; i < NF * HID; i += 256) sW[i] = W[i];
    const int row0 = blockIdx.x * 32;
    {
        const float4* xv = (const float4*)(x + (size_t)row0 * NF);
        for (int i = t; i < 32 * 32; i += 256) {
            int r = i >> 5, c = i & 31;
            float4 v = make_float4(0.f, 0.f, 0.f, 0.f);
            if (row0 + r < N) v = xv[(size_t)r * 32 + c];
            *(float4*)&sx[r][c * 4] = v;
        }
    }
    __syncthreads();
    const int col4 = (t & 7) * 4;
    const int row = t >> 3;
    float a0 = 0.f, a1 = 0.f, a2 = 0.f, a3 = 0.f;
#pragma unroll 8
    for (int k = 0; k < NF; ++k) {
        float xs = sx[row][k];
        float4 w = *(const float4*)&sW[k * HID + col4];
        a0 += xs * w.x; a1 += xs * w.y; a2 += xs * w.z; a3 += xs * w.w;
    }
    int r = row0 + row;
    if (r < N) {
        float d = dis[r];
        unsigned u0 = bf16rne(a0 * d) | (bf16rne(a1 * d) << 16);
        unsigned u1 = bf16rne(a2 * d) | (bf16rne(a3 * d) << 16);
        *(uint2*)&h1b[(size_t)r * 16 + (t & 7) * 2] = make_uint2(u0, u1);
    }
}

// --- agg1: t = bf16(dis * relu(dis*(self+sum) + b1)); 32 ch bf16, 4 lanes/node ---
__global__ __launch_bounds__(256) void k_agg1(const uint4* __restrict__ h1b,
                                              const int* __restrict__ roff,
                                              const int* __restrict__ csr,
                                              const float* __restrict__ dis,
                                              const float* __restrict__ b1,
                                              uint4* __restrict__ t_out, int N) {
    int tt = blockIdx.x * 256 + threadIdx.x;
    int node = tt >> 2;
    if (node >= N) return;
    int j = tt & 3;
    uint4 u = h1b[(size_t)node * 4 + j];        // self-loop
    float a0, a1, a2, a3, a4, a5, a6, a7;
    a0 = __uint_as_float(u.x << 16); a1 = __uint_as_float(u.x & 0xffff0000u);
    a2 = __uint_as_float(u.y << 16); a3 = __uint_as_float(u.y & 0xffff0000u);
    a4 = __uint_as_float(u.z << 16); a5 = __uint_as_float(u.z & 0xffff0000u);
    a6 = __uint_as_float(u.w << 16); a7 = __uint_as_float(u.w & 0xffff0000u);
    int e0 = roff[node], e1 = roff[node + 1];
    int e = e0;
    for (; e + 4 <= e1; e += 4) {
        int s0 = __builtin_nontemporal_load(&csr[e + 0]);
        int s1 = __builtin_nontemporal_load(&csr[e + 1]);
        int s2 = __builtin_nontemporal_load(&csr[e + 2]);
        int s3 = __builtin_nontemporal_load(&csr[e + 3]);
        uint4 v0 = h1b[(size_t)s0 * 4 + j];
        uint4 v1 = h1b[(size_t)s1 * 4 + j];
        uint4 v2 = h1b[(size_t)s2 * 4 + j];
        uint4 v3 = h1b[(size_t)s3 * 4 + j];
        ACC8(v0) ACC8(v1) ACC8(v2) ACC8(v3)
    }
    for (; e < e1; ++e) {
        int s = __builtin_nontemporal_load(&csr[e]);
        uint4 v = h1b[(size_t)s * 4 + j];
        ACC8(v)
    }
    float d = dis[node];
    float4 bb0 = *(const float4*)&b1[j * 8];
    float4 bb1 = *(const float4*)&b1[j * 8 + 4];
    float r0 = fmaxf(a0 * d + bb0.x, 0.f) * d, r1 = fmaxf(a1 * d + bb0.y, 0.f) * d;
    float r2 = fmaxf(a2 * d + bb0.z, 0.f) * d, r3 = fmaxf(a3 * d + bb0.w, 0.f) * d;
    float r4 = fmaxf(a4 * d + bb1.x, 0.f) * d, r5 = fmaxf(a5 * d + bb1.y, 0.f) * d;
    float r6 = fmaxf(a6 * d + bb1.z, 0.f) * d, r7 = fmaxf(a7 * d + bb1.w, 0.f) * d;
    uint4 o;
    o.x = bf16rne(r0) | (bf16rne(r1) << 16);
    o.y = bf16rne(r2) | (bf16rne(r3) << 16);
    o.z = bf16rne(r4) | (bf16rne(r5) << 16);
    o.w = bf16rne(r6) | (bf16rne(r7) << 16);
    t_out[(size_t)node * 4 + j] = o;
}

// --- agg2: s2 = dis*(self + sum t[src]); 32 ch fp32 out, 4 lanes/node ---
__global__ __launch_bounds__(256) void k_agg2(const uint4* __restrict__ tb,
                                              const int* __restrict__ roff,
                                              const int* __restrict__ csr,
                                              const float* __restrict__ dis,
                                              float* __restrict__ s2, int N) {
    int tt = blockIdx.x * 256 + threadIdx.x;
    int node = tt >> 2;
    if (node >= N) return;
    int j = tt & 3;
    uint4 u = tb[(size_t)node * 4 + j];         // self-loop
    float a0, a1, a2, a3, a4, a5, a6, a7;
    a0 = __uint_as_float(u.x << 16); a1 = __uint_as_float(u.x & 0xffff0000u);
    a2 = __uint_as_float(u.y << 16); a3 = __uint_as_float(u.y & 0xffff0000u);
    a4 = __uint_as_float(u.z << 16); a5 = __uint_as_float(u.z & 0xffff0000u);
    a6 = __uint_as_float(u.w << 16); a7 = __uint_as_float(u.w & 0xffff0000u);
    int e0 = roff[node], e1 = roff[node + 1];
    int e = e0;
    for (; e + 4 <= e1; e += 4) {
        int s0 = __builtin_nontemporal_load(&csr[e + 0]);
        int s1 = __builtin_nontemporal_load(&csr[e + 1]);
        int s2i = __builtin_nontemporal_load(&csr[e + 2]);
        int s3 = __builtin_nontemporal_load(&csr[e + 3]);
        uint4 v0 = tb[(size_t)s0 * 4 + j];
        uint4 v1 = tb[(size_t)s1 * 4 + j];
        uint4 v2 = tb[(size_t)s2i * 4 + j];
        uint4 v3 = tb[(size_t)s3 * 4 + j];
        ACC8(v0) ACC8(v1) ACC8(v2) ACC8(v3)
    }
    for (; e < e1; ++e) {
        int s = __builtin_nontemporal_load(&csr[e]);
        uint4 v = tb[(size_t)s * 4 + j];
        ACC8(v)
    }
    float d = dis[node];
    float* op = &s2[(size_t)node * HID + j * 8];
    *(float4*)op       = make_float4(a0 * d, a1 * d, a2 * d, a3 * d);
    *(float4*)(op + 4) = make_float4(a4 * d, a5 * d, a6 * d, a7 * d);
}

// --- GEMM2: out[r] = s2[r] @ W2 + b2, s2: N x 32, W2: 32 x 64 ---
__global__ __launch_bounds__(256) void k_gemm2(const float* __restrict__ a,
                                               const float* __restrict__ W,
                                               const float* __restrict__ b2,
                                               float* __restrict__ out, int N) {
    __shared__ float sW[HID * EMB];
    __shared__ float sx[32][36];
    const int t = threadIdx.x;
    for (int i = t; i < HID * EMB; i += 256) sW[i] = W[i];
    const int row0 = blockIdx.x * 32;
    {
        const float4* av = (const float4*)(a + (size_t)row0 * HID);
        int r = t >> 3, c = t & 7;
        float4 v = make_float4(0.f, 0.f, 0.f, 0.f);
        if (row0 + r < N) v = av[(size_t)r * 8 + c];
        *(float4*)&sx[r][c * 4] = v;
    }
    __syncthreads();
    const int col4 = (t & 15) * 4;
    const int r0 = t >> 4;  // 0..15, also r0+16
    float a00 = 0.f, a01 = 0.f, a02 = 0.f, a03 = 0.f;
    float a10 = 0.f, a11 = 0.f, a12 = 0.f, a13 = 0.f;
#pragma unroll
    for (int k = 0; k < HID; ++k) {
        float4 w = *(const float4*)&sW[k * EMB + col4];
        float xa = sx[r0][k];
        float xb = sx[r0 + 16][k];
        a00 += xa * w.x; a01 += xa * w.y; a02 += xa * w.z; a03 += xa * w.w;
        a10 += xb * w.x; a11 += xb * w.y; a12 += xb * w.z; a13 += xb * w.w;
    }
    float4 bb = *(const float4*)&b2[col4];
    int ra = row0 + r0, rb = row0 + r0 + 16;
    if (ra < N) {
        vf4 o; o.x = a00 + bb.x; o.y = a01 + bb.y; o.z = a02 + bb.z; o.w = a03 + bb.w;
        __builtin_nontemporal_store(o, (vf4*)&out[(size_t)ra * EMB + col4]);
    }
    if (rb < N) {
        vf4 o; o.x = a10 + bb.x; o.y = a11 + bb.y; o.z = a12 + bb.z; o.w = a13 + bb.w;
        __builtin_nontemporal_store(o, (vf4*)&out[(size_t)rb * EMB + col4]);
    }
}

extern "C" void kernel_launch(void* const* d_in, const int* in_sizes, int n_in,
                              void* d_out, int out_size, void* d_ws, size_t ws_size,
                              hipStream_t stream) {
    const float* x  = (const float*)d_in[0];
    const void*  ei = d_in[1];
    const float* W1 = (const float*)d_in[2];
    const float* b1 = (const float*)d_in[3];
    const float* W2 = (const float*)d_in[4];
    const float* b2 = (const float*)d_in[5];
    float* out = (float*)d_out;

    const int N = in_sizes[0] / NF;              // 100000
    const int E = in_sizes[1] / 2;               // 3200000
    const int nbuk = (N + BNODES - 1) >> BSHIFT; // 98

    char* ws = (char*)d_ws;
    size_t off = 0;
    auto take = [&](size_t bytes) -> void* {
        void* p = ws + off;
        off += (bytes + 255) & ~(size_t)255;
        return p;
    };
    // zeroed region first (single memset)
    int* cnt_ovf = (int*)take((size_t)N * 4);
    int* bcur    = (int*)take((size_t)NBUKMAX * 4);
    int* ovfcnt  = (int*)take(4);
    int* flag    = (int*)take(4);
    size_t zbytes = off;
    // rest
    int*                bbase  = (int*)take((size_t)NBUKMAX * 4);
    int*                roff   = (int*)take((size_t)(N + 1) * 4);
    int*                cursor = (int*)take((size_t)N * 4);
    float*              dis    = (float*)take((size_t)N * 4);
    int*                histc  = (int*)take((size_t)NBUKMAX * CHUNKS * BNODES * 4);
    unsigned*           pairs  = (unsigned*)take((size_t)nbuk * CAP * 4);
    unsigned long long* ovf    = (unsigned long long*)take((size_t)E * 8);
    int*                csr    = (int*)take((size_t)E * 4);
    unsigned*           h1b    = (unsigned*)take((size_t)N * HID * 2);
    unsigned*           tb     = (unsigned*)take((size_t)N * HID * 2);
    float*              s2     = (float*)take((size_t)N * HID * 4);

    (void)hipMemsetAsync(cnt_ovf, 0, zbytes, stream);

    const int gridBC = ((nbuk + 7) / 8) * 64;    // swizzled (b,c) grid

    k_detect<<<16, 256, 0, stream>>>((const unsigned*)ei, flag);
    k_part<<<(E + TILE - 1) / TILE, 256, 0, stream>>>(ei, flag, pairs, bcur, cnt_ovf,
                                                      ovf, ovfcnt, E, nbuk);
    k_bscan<<<1, 128, 0, stream>>>(bcur, bbase, roff, nbuk, E, N);
    k_hist<<<gridBC, 256, 0, stream>>>(pairs, bcur, histc, nbuk);
    k_nscan<<<nbuk, 256, 0, stream>>>(histc, bbase, cnt_ovf, roff, cursor, dis, N);
    k_scat2<<<gridBC, 256, 0, stream>>>(pairs, bcur, histc, csr, nbuk);
    k_ovf<<<8, 256, 0, stream>>>(ovf, ovfcnt, cursor, csr);

    k_gemm1<<<(N + 31) / 32, 256, 0, stream>>>(x, W1, dis, h1b, N);
    k_agg1<<<((size_t)N * 4 + 255) / 256, 256, 0, stream>>>((const uint4*)h1b, roff, csr,
                                                            dis, b1, (uint4*)tb, N);
    k_agg2<<<((size_t)N * 4 + 255) / 256, 256, 0, stream>>>((const uint4*)tb, roff, csr,
                                                            dis, s2, N);
    k_gemm2<<<(N + 31) / 32, 256, 0, stream>>>(s2, W2, b2, out, N);
}